// Round 5
// baseline (265.803 us; speedup 1.0000x reference)
//
#include <hip/hip_runtime.h>
#include <hip/hip_bf16.h>
#include <hip/hip_fp16.h>

// GraphConvolution: out = segment_sum(vals[:,None] * support[cols], rows)
// N=100000 nodes, E=1600000 edges, F=128 features, fp32.
//
// Round 12: R11 post-mortem — 2x in-flight bytes did NOT speed the gather
//  (72.6 vs 73.9): it is at its cache-path BW ceiling, not latency-bound;
//  and splitting bin/convert cost 9us of serialization (R10 ran them
//  concurrently in one grid). Fixed harness overhead ~100us; controllable
//  ~110us. This round:
//   1. Re-merge bin+convert into phase1 (one grid, proven -9us).
//   2. Gather: 128-row buckets, 512 threads, CELL=16 -> LDS ~26KB,
//      4 blocks/CU (vs 1.5), 782 blocks, halved tail quantum. Same work.
//  Binning keys: d=row>>7, ND=782, per-cell lambda=10.4, P(X>16)~4% ->
//  ~12K overflow edges via proven ovf path.

#define D_FEAT 128
#define F4 32            // float4s per feature vector
#define H4 32            // half4s per feature vector
#define H8 16            // half8s per feature vector
#define STRIDE 64        // padded slots per row (fallback 1 only)
#define CELL 16          // slots per (bucket, block) cell (Poisson(10.4))
#define OVF_CAP 131072   // overflow list capacity
#define EPT 8            // edges per thread in binning
#define MAXIT 7          // gather S1 iterations: covers NBLK*CELL <= 3584
#define MAXSLOT 3136     // LDS csr capacity (entries) = 196*16
#define BROWS 128        // rows per gather bucket

typedef float    vfloat4 __attribute__((ext_vector_type(4)));
typedef _Float16 half4v  __attribute__((ext_vector_type(4)));
typedef _Float16 half8v  __attribute__((ext_vector_type(8)));

// ============ phase 1: coarse bin (LDS ranks) + fused fp32->fp16 convert ============

__global__ __launch_bounds__(1024) void
phase1_bin_kernel(const float4* __restrict__ support4,
                  half8v* __restrict__ supporth,
                  const int* __restrict__ rows,
                  const int* __restrict__ cols,
                  const float* __restrict__ vals,
                  int2* __restrict__ coarse,     // [ND][NBLK][CELL] packed
                  int* __restrict__ cellcnt,     // [ND][NBLK]
                  int4* __restrict__ ovf,
                  int* __restrict__ ovf_count,
                  int E, int BT, int NBLK, int ND, int n8) {
    int b = blockIdx.x;
    int tid = threadIdx.x;

    if (b >= NBLK) {
        // -------- convert slice --------
        int m = (b - NBLK) * 1024 + tid;
        if (m < n8) {
            float4 a0 = support4[(size_t)m * 2];
            float4 a1 = support4[(size_t)m * 2 + 1];
            half8v h;
            h[0] = (_Float16)a0.x; h[1] = (_Float16)a0.y;
            h[2] = (_Float16)a0.z; h[3] = (_Float16)a0.w;
            h[4] = (_Float16)a1.x; h[5] = (_Float16)a1.y;
            h[6] = (_Float16)a1.z; h[7] = (_Float16)a1.w;
            supporth[m] = h;
        }
        return;
    }

    // -------- bin slice --------
    __shared__ int hist[1024];
    for (int i = tid; i < 1024; i += 1024) hist[i] = 0;
    __syncthreads();

    int t = b * 1024 + tid;
    int   r[EPT];
    int   c[EPT];
    float v[EPT];
    int   rk[EPT];

    #pragma unroll
    for (int i = 0; i < EPT; ++i) {
        int e = t + i * BT;
        r[i] = (e < E) ? rows[e] : -1;
    }
    #pragma unroll
    for (int i = 0; i < EPT; ++i) {
        int e = t + i * BT;
        if (e < E) { c[i] = cols[e]; v[i] = vals[e]; }
    }
    // LDS int return-atomics: native ds_add_rtn_u32, ~30 cyc
    #pragma unroll
    for (int i = 0; i < EPT; ++i)
        rk[i] = (r[i] >= 0) ? atomicAdd(&hist[r[i] >> 7], 1) : 0;

    #pragma unroll
    for (int i = 0; i < EPT; ++i) {
        if (r[i] < 0) continue;
        int d = r[i] >> 7;
        if (rk[i] < CELL) {
            int2 q;
            q.x = ((r[i] & 127) << 17) | c[i];   // c < 2^17, row&127 in 17..23
            q.y = __float_as_int(v[i]);
            coarse[((size_t)d * NBLK + b) * CELL + rk[i]] = q;
        } else {
            int o = atomicAdd(ovf_count, 1);  // far, rare (~1e4 edges)
            if (o < OVF_CAP) {
                int4 q;
                q.x = r[i]; q.y = c[i]; q.z = __float_as_int(v[i]); q.w = 0;
                ovf[o] = q;
            }
        }
    }
    __syncthreads();
    for (int d = tid; d < ND; d += 1024) {
        int h = hist[d];
        cellcnt[(size_t)d * NBLK + b] = (h < CELL) ? h : CELL;
    }
}

// ====== fused bucket CSR gather: rank + scan + LDS CSR + half8 gather ======
// One block per 128-row bucket d. 512 threads, ~26KB LDS -> 4 blocks/CU.
//  S1: per-lane coalesced read of bucket's coarse cells, LDS int atomic rank.
//  S2: 32-lane shuffle prefix-scan of cnt[128] -> off[129].
//  S3: scatter (col,val) entries into LDS csr[off[r]+rank].
//  S4: 32 groups x 16 lanes; group handles 4 rows; per row read (col,val)
//      by LDS broadcast, 8 independent half8 (16B) supporth loads per lane,
//      fp32 accumulate (2 rotating sets), coalesced nontemporal stores.

__global__ __launch_bounds__(512) void
bucket_csr_gather_kernel(const half8v* __restrict__ supporth,
                         const int2* __restrict__ coarse,
                         const int* __restrict__ cellcnt,
                         float4* __restrict__ out4,
                         int NBLK, int N) {
    __shared__ int  cnt[BROWS + 1];
    __shared__ int  off[BROWS + 1];
    __shared__ int2 csr[MAXSLOT + 8];   // +8 pad: gather reads up to end-1+7

    const int d   = blockIdx.x;
    const int tid = threadIdx.x;
    const int2* cbase = coarse  + (size_t)d * NBLK * CELL;
    const int*  ccnt  = cellcnt + (size_t)d * NBLK;
    const int total = NBLK * CELL;

    if (tid < BROWS + 1) cnt[tid] = 0;
    __syncthreads();

    // ---- S1: load + rank ----
    int2 ent[MAXIT];
    int  err[MAXIT];
    int  ernk[MAXIT];
    #pragma unroll
    for (int it = 0; it < MAXIT; ++it) {
        int s = tid + it * 512;
        err[it] = -1;
        if (s < total && (s & (CELL - 1)) < ccnt[s >> 4]) {   // CELL == 16
            int2 q = cbase[s];
            int r = (q.x >> 17) & 127;
            ent[it].x = q.x & 0x1FFFF;
            ent[it].y = q.y;
            err[it] = r;
            ernk[it] = atomicAdd(&cnt[r], 1);                 // LDS int rtn atomic
        }
    }
    __syncthreads();

    // ---- S2: prefix scan cnt[128] -> off (first 32 lanes) ----
    if (tid < 32) {
        int4 c4 = ((int4*)cnt)[tid];
        int t0 = c4.x;
        int t1 = t0 + c4.y;
        int t2 = t1 + c4.z;
        int t3 = t2 + c4.w;
        int inc = t3;
        #pragma unroll
        for (int dd = 1; dd < 32; dd <<= 1) {
            int t = __shfl_up(inc, dd, 32);
            if (tid >= dd) inc += t;
        }
        int excl = inc - t3;
        off[tid * 4 + 0] = excl;
        off[tid * 4 + 1] = excl + t0;
        off[tid * 4 + 2] = excl + t1;
        off[tid * 4 + 3] = excl + t2;
        if (tid == 31) off[BROWS] = inc;
    }
    __syncthreads();

    // ---- S3: scatter into LDS CSR ----
    #pragma unroll
    for (int it = 0; it < MAXIT; ++it) {
        if (err[it] >= 0)
            csr[off[err[it]] + ernk[it]] = ent[it];
    }
    __syncthreads();

    // ---- S4: gather, 16-lane groups, half8 loads ----
    const int g = tid >> 4;       // group 0..31
    const int i = tid & 15;       // lane in group; feats 8i..8i+7
    const int base = d << 7;
    for (int rq = 0; rq < 4; ++rq) {
        int r   = (rq << 5) + g;            // 0..127
        int beg = off[r];
        int end = off[r + 1];
        vfloat4 a00 = {0.f,0.f,0.f,0.f}, a01 = {0.f,0.f,0.f,0.f};
        vfloat4 a10 = {0.f,0.f,0.f,0.f}, a11 = {0.f,0.f,0.f,0.f};
        for (int k0 = beg; k0 < end; k0 += 8) {
            int   cc[8];
            float vv[8];
            #pragma unroll
            for (int u = 0; u < 8; ++u) {
                int2 e = csr[k0 + u];       // LDS broadcast (uniform per group)
                bool ib = (k0 + u) < end;
                cc[u] = ib ? e.x : 0;
                vv[u] = ib ? __int_as_float(e.y) : 0.f;
            }
            half8v s[8];
            #pragma unroll
            for (int u = 0; u < 8; ++u)
                s[u] = supporth[(size_t)cc[u] * H8 + i];
            #pragma unroll
            for (int u = 0; u < 8; ++u) {
                float v = vv[u];
                if (u & 1) {
                    a10.x += v * (float)s[u][0];
                    a10.y += v * (float)s[u][1];
                    a10.z += v * (float)s[u][2];
                    a10.w += v * (float)s[u][3];
                    a11.x += v * (float)s[u][4];
                    a11.y += v * (float)s[u][5];
                    a11.z += v * (float)s[u][6];
                    a11.w += v * (float)s[u][7];
                } else {
                    a00.x += v * (float)s[u][0];
                    a00.y += v * (float)s[u][1];
                    a00.z += v * (float)s[u][2];
                    a00.w += v * (float)s[u][3];
                    a01.x += v * (float)s[u][4];
                    a01.y += v * (float)s[u][5];
                    a01.z += v * (float)s[u][6];
                    a01.w += v * (float)s[u][7];
                }
            }
        }
        int row = base + r;
        if (row < N) {
            vfloat4 r0, r1;
            r0.x = a00.x + a10.x; r0.y = a00.y + a10.y;
            r0.z = a00.z + a10.z; r0.w = a00.w + a10.w;
            r1.x = a01.x + a11.x; r1.y = a01.y + a11.y;
            r1.z = a01.z + a11.z; r1.w = a01.w + a11.w;
            float4* dst = &out4[(size_t)row * F4 + (i << 1)];
            __builtin_nontemporal_store(r0, (vfloat4*)dst);
            __builtin_nontemporal_store(r1, (vfloat4*)(dst + 1));
        }
    }
}

// ============ overflow cleanup (after gather; adds onto its output) ============

__global__ void ovf_scatter_kernel(const float* __restrict__ support,
                                   const int4* __restrict__ ovf,
                                   const int* __restrict__ ovf_count,
                                   float* __restrict__ out, int cap) {
    int gid = blockIdx.x * blockDim.x + threadIdx.x;
    int i = gid >> 5;
    int j = gid & 31;
    int istride = (gridDim.x * blockDim.x) >> 5;
    int cnt = *ovf_count;
    if (cnt > cap) cnt = cap;
    for (; i < cnt; i += istride) {
        int4 q = ovf[i];
        float v = __int_as_float(q.z);
        const float4* s4 = (const float4*)support + (size_t)q.y * F4 + j;
        float4 s = *s4;
        float* o = out + (size_t)q.x * D_FEAT + j * 4;
        unsafeAtomicAdd(o + 0, v * s.x);
        unsafeAtomicAdd(o + 1, v * s.y);
        unsafeAtomicAdd(o + 2, v * s.z);
        unsafeAtomicAdd(o + 3, v * s.w);
    }
}

// ================= fallback 1: R5 fp16 path (device return-atomics) =================

__global__ void convert_kernel(const float4* __restrict__ in,
                               half8v* __restrict__ out, int n8) {
    int t = blockIdx.x * blockDim.x + threadIdx.x;
    if (t >= n8) return;
    float4 a = in[(size_t)t * 2];
    float4 b = in[(size_t)t * 2 + 1];
    half8v h;
    h[0] = (_Float16)a.x; h[1] = (_Float16)a.y;
    h[2] = (_Float16)a.z; h[3] = (_Float16)a.w;
    h[4] = (_Float16)b.x; h[5] = (_Float16)b.y;
    h[6] = (_Float16)b.z; h[7] = (_Float16)b.w;
    out[t] = h;
}

__global__ void gather_half_kernel(const half4v* __restrict__ supporth,
                                   const int* __restrict__ cursor,
                                   const int2* __restrict__ pairs,
                                   float4* __restrict__ out4, int n_nodes) {
    unsigned int t = blockIdx.x * blockDim.x + threadIdx.x;
    unsigned int row = t >> 5;
    unsigned int j = t & 31;
    if (row >= (unsigned int)n_nodes) return;
    int deg = cursor[row];
    if (deg > STRIDE) deg = STRIDE;
    const int2* pr = pairs + (size_t)row * STRIDE;
    int2 z = {0, 0};
    int2 p0 = ((int)j < deg) ? pr[j] : z;
    int2 p1 = ((int)(j + 32) < deg) ? pr[j + 32] : z;
    int   c0 = p0.x;  float v0 = __int_as_float(p0.y);
    int   c1 = p1.x;  float v1 = __int_as_float(p1.y);
    int degr = (deg + 7) & ~7;
    float4 acc[4];
    #pragma unroll
    for (int u = 0; u < 4; ++u) acc[u] = {0.f, 0.f, 0.f, 0.f};
    for (int k = 0; k < degr; k += 8) {
        int   cc[8];
        float vv[8];
        #pragma unroll
        for (int u = 0; u < 8; ++u) {
            int kk = k + u;
            cc[u] = __shfl(kk < 32 ? c0 : c1, kk & 31, 32);
            vv[u] = __shfl(kk < 32 ? v0 : v1, kk & 31, 32);
        }
        half4v s[8];
        #pragma unroll
        for (int u = 0; u < 8; ++u)
            s[u] = supporth[(size_t)cc[u] * H4 + j];
        #pragma unroll
        for (int u = 0; u < 8; ++u) {
            acc[u & 3].x += vv[u] * (float)s[u][0];
            acc[u & 3].y += vv[u] * (float)s[u][1];
            acc[u & 3].z += vv[u] * (float)s[u][2];
            acc[u & 3].w += vv[u] * (float)s[u][3];
        }
    }
    vfloat4 res;
    res.x = (acc[0].x + acc[1].x) + (acc[2].x + acc[3].x);
    res.y = (acc[0].y + acc[1].y) + (acc[2].y + acc[3].y);
    res.z = (acc[0].z + acc[1].z) + (acc[2].z + acc[3].z);
    res.w = (acc[0].w + acc[1].w) + (acc[2].w + acc[3].w);
    __builtin_nontemporal_store(res, (vfloat4*)&out4[(size_t)row * F4 + j]);
}

__global__ void bucket_ilp_kernel(const int* __restrict__ rows,
                                  const int* __restrict__ cols,
                                  const float* __restrict__ vals,
                                  int* __restrict__ cursor,
                                  int* __restrict__ ovf_count,
                                  int2* __restrict__ pairs,
                                  int4* __restrict__ ovf,
                                  int n_edges, int gstride) {
    int tid = blockIdx.x * blockDim.x + threadIdx.x;
    int   r[EPT];
    int   c[EPT];
    float v[EPT];
    int   slot[EPT];
    #pragma unroll
    for (int i = 0; i < EPT; ++i) {
        int e = tid + i * gstride;
        r[i] = (e < n_edges) ? rows[e] : -1;
    }
    #pragma unroll
    for (int i = 0; i < EPT; ++i) {
        int e = tid + i * gstride;
        if (e < n_edges) { c[i] = cols[e]; v[i] = vals[e]; }
    }
    #pragma unroll
    for (int i = 0; i < EPT; ++i)
        slot[i] = (r[i] >= 0) ? atomicAdd(&cursor[r[i]], 1) : 0;
    #pragma unroll
    for (int i = 0; i < EPT; ++i) {
        if (r[i] < 0) continue;
        int2 p;
        p.x = c[i];
        p.y = __float_as_int(v[i]);
        if (slot[i] < STRIDE) {
            pairs[(size_t)r[i] * STRIDE + slot[i]] = p;
        } else {
            int o = atomicAdd(ovf_count, 1);
            if (o < OVF_CAP) {
                int4 q; q.x = r[i]; q.y = p.x; q.z = p.y; q.w = 0;
                ovf[o] = q;
            }
        }
    }
}

// ==================== fallback 2: atomic scatter (R0) ====================

__global__ void gc_scatter_kernel(const float* __restrict__ support,
                                  const float* __restrict__ vals,
                                  const int* __restrict__ rows,
                                  const int* __restrict__ cols,
                                  float* __restrict__ out, int n_edges) {
    unsigned int t = blockIdx.x * blockDim.x + threadIdx.x;
    unsigned int e = t >> 5;
    unsigned int j = t & 31;
    if (e >= (unsigned int)n_edges) return;
    int r = rows[e];
    int c = cols[e];
    float v = vals[e];
    const float4* s4 = reinterpret_cast<const float4*>(support) + (size_t)c * F4 + j;
    float4 s = *s4;
    float* o = out + (size_t)r * D_FEAT + j * 4;
    unsafeAtomicAdd(o + 0, v * s.x);
    unsafeAtomicAdd(o + 1, v * s.y);
    unsafeAtomicAdd(o + 2, v * s.z);
    unsafeAtomicAdd(o + 3, v * s.w);
}

// ============================ launch ============================

extern "C" void kernel_launch(void* const* d_in, const int* in_sizes, int n_in,
                              void* d_out, int out_size, void* d_ws, size_t ws_size,
                              hipStream_t stream) {
    const float* support = (const float*)d_in[0];
    const float* vals    = (const float*)d_in[1];
    const int*   rows    = (const int*)d_in[2];
    const int*   cols    = (const int*)d_in[3];
    float* out = (float*)d_out;

    int E = in_sizes[1];
    int N = in_sizes[0] / D_FEAT;
    int n8 = N * D_FEAT / 8;
    int ND = (N + BROWS - 1) / BROWS;             // 128-row buckets (782)
    int NBLK = (E + 1024 * EPT - 1) / (1024 * EPT);  // bin blocks (196)
    int BT = NBLK * 1024;

    char* ws = (char*)d_ws;
    size_t cur = 0;
    auto carve = [&](size_t bytes) -> void* {
        void* p = ws + cur;
        cur += (bytes + 255) & ~(size_t)255;
        return p;
    };

    // ---- primary: LDS-ranked binning + fused LDS-CSR bucket gather ----
    {
        size_t save = cur;
        int2*   coarse    = (int2*)carve((size_t)ND * NBLK * CELL * 8);
        int*    cellcnt   = (int*)carve((size_t)ND * NBLK * 4);
        int4*   ovf       = (int4*)carve((size_t)OVF_CAP * 16);
        int*    ovf_count = (int*)carve(256);
        half8v* supporth  = (half8v*)carve((size_t)N * D_FEAT * 2);
        if (cur <= ws_size && ND <= 1024 && NBLK * CELL <= MAXSLOT) {
            (void)hipMemsetAsync(ovf_count, 0, 4, stream);
            int cblocks = (n8 + 1023) / 1024;
            phase1_bin_kernel<<<NBLK + cblocks, 1024, 0, stream>>>(
                (const float4*)support, supporth, rows, cols, vals,
                coarse, cellcnt, ovf, ovf_count, E, BT, NBLK, ND, n8);
            bucket_csr_gather_kernel<<<ND, 512, 0, stream>>>(
                supporth, coarse, cellcnt, (float4*)out, NBLK, N);
            ovf_scatter_kernel<<<512, 256, 0, stream>>>(
                support, ovf, ovf_count, out, OVF_CAP);
            return;
        }
        cur = save;
    }

    // ---- fallback 1: R5 fp16 padded buckets (device return-atomics) ----
    {
        size_t save = cur;
        int*    cursor   = (int*)carve((size_t)(N + 1) * 4);
        int2*   pairs    = (int2*)carve((size_t)N * STRIDE * 8);
        int4*   ovf      = (int4*)carve((size_t)8192 * 16);
        half8v* supporth = (half8v*)carve((size_t)N * D_FEAT * 2);
        if (cur <= ws_size) {
            int* ovf_count = cursor + N;
            int bthreads = (E + EPT - 1) / EPT;
            int bblocks = (bthreads + 255) / 256;
            int gstride = bblocks * 256;
            (void)hipMemsetAsync(cursor, 0, (size_t)(N + 1) * 4, stream);
            convert_kernel<<<(n8 + 255) / 256, 256, 0, stream>>>(
                (const float4*)support, supporth, n8);
            bucket_ilp_kernel<<<bblocks, 256, 0, stream>>>(
                rows, cols, vals, cursor, ovf_count, pairs, ovf, E, gstride);
            unsigned int gthreads = (unsigned int)N * 32;
            gather_half_kernel<<<(gthreads + 255) / 256, 256, 0, stream>>>(
                (const half4v*)supporth, cursor, pairs, (float4*)out, N);
            ovf_scatter_kernel<<<512, 256, 0, stream>>>(
                support, ovf, ovf_count, out, 8192);
            return;
        }
        cur = save;
    }

    // ---- fallback 2: atomic scatter ----
    (void)hipMemsetAsync(d_out, 0, (size_t)out_size * sizeof(float), stream);
    unsigned int total = (unsigned int)E * 32;
    gc_scatter_kernel<<<(total + 255) / 256, 256, 0, stream>>>(
        support, vals, rows, cols, out, E);
}

// Round 6
// 203.193 us; speedup vs baseline: 1.3081x; 1.3081x over previous
//
#include <hip/hip_runtime.h>
#include <hip/hip_bf16.h>
#include <hip/hip_fp16.h>

// GraphConvolution: out = segment_sum(vals[:,None] * support[cols], rows)
// N=100000 nodes, E=1600000 edges, F=128 features, fp32.
//
// Round 13: R12 post-mortem — CELL=16 raised overflow ~1K->~12K edges; each
//  is a far return-atomic on ONE global counter -> ~55us serialized drain =
//  the whole regression (phase1 78us, all pipes idle). ALSO revealed phase1
//  has been ~60-78us all along (fixed harness overhead is ~55us, not 100).
//  Its limiter: 12.8M scattered 8B coarse stores (WRITE 67MB vs 39 ideal =
//  64B-sector amplification). This round:
//   - Revert to R10/R11 geometry: d=row>>8, ND=391, CELL=32 (overflow ~1K),
//     gather = R11's measured-72.6us kernel VERBATIM.
//   - phase1 v2: block-local counting sort in LDS (hist rank -> clamped
//     prefix scan -> scatter into sorted[8192] -> COALESCED writeout, with
//     bucket-of-slot via 9-step LDS binary search). Scattered 8B stores ->
//     ~168B coalesced runs.

#define D_FEAT 128
#define F4 32            // float4s per feature vector
#define H4 32            // half4s per feature vector
#define H8 16            // half8s per feature vector
#define STRIDE 64        // padded slots per row (fallback 1 only)
#define CELL 32          // slots per (bucket, block) cell (Poisson(21))
#define OVF_CAP 131072   // overflow list capacity
#define EPT 8            // edges per thread in binning
#define MAXIT 8          // gather S1 iterations: covers NBLK*CELL <= 8192
#define MAXSLOT 8192     // LDS csr capacity (entries)
#define BROWS 256        // rows per gather bucket

typedef float    vfloat4 __attribute__((ext_vector_type(4)));
typedef _Float16 half4v  __attribute__((ext_vector_type(4)));
typedef _Float16 half8v  __attribute__((ext_vector_type(8)));

// ============ phase 1 v2: LDS counting-sort bin + fused fp32->fp16 convert ============

__global__ __launch_bounds__(1024) void
phase1_bin_kernel(const float4* __restrict__ support4,
                  half8v* __restrict__ supporth,
                  const int* __restrict__ rows,
                  const int* __restrict__ cols,
                  const float* __restrict__ vals,
                  int2* __restrict__ coarse,     // [ND][NBLK][CELL] packed
                  int* __restrict__ cellcnt,     // [ND][NBLK]
                  int4* __restrict__ ovf,
                  int* __restrict__ ovf_count,
                  int E, int BT, int NBLK, int ND, int n8) {
    int b = blockIdx.x;
    int tid = threadIdx.x;

    if (b >= NBLK) {
        // -------- convert slice --------
        int m = (b - NBLK) * 1024 + tid;
        if (m < n8) {
            float4 a0 = support4[(size_t)m * 2];
            float4 a1 = support4[(size_t)m * 2 + 1];
            half8v h;
            h[0] = (_Float16)a0.x; h[1] = (_Float16)a0.y;
            h[2] = (_Float16)a0.z; h[3] = (_Float16)a0.w;
            h[4] = (_Float16)a1.x; h[5] = (_Float16)a1.y;
            h[6] = (_Float16)a1.z; h[7] = (_Float16)a1.w;
            supporth[m] = h;
        }
        return;
    }

    // -------- bin slice: counting sort in LDS, coalesced writeout --------
    __shared__ int  hist[512];
    __shared__ int  off[513];
    __shared__ int2 sorted[1024 * EPT];   // 64 KB

    for (int i = tid; i < 512; i += 1024) hist[i] = 0;
    __syncthreads();

    int t = b * 1024 + tid;
    int   r[EPT];
    int   c[EPT];
    float v[EPT];
    int   rk[EPT];

    #pragma unroll
    for (int i = 0; i < EPT; ++i) {
        int e = t + i * BT;
        r[i] = (e < E) ? rows[e] : -1;
    }
    #pragma unroll
    for (int i = 0; i < EPT; ++i) {
        int e = t + i * BT;
        if (e < E) { c[i] = cols[e]; v[i] = vals[e]; }
    }
    // LDS int return-atomics: native ds_add_rtn_u32
    #pragma unroll
    for (int i = 0; i < EPT; ++i)
        rk[i] = (r[i] >= 0) ? atomicAdd(&hist[r[i] >> 8], 1) : 0;
    __syncthreads();

    // clamped prefix scan of 512 bins (wave 0; 8 bins/lane serial + wave scan)
    if (tid < 64) {
        int l[8];
        int s = 0;
        #pragma unroll
        for (int k = 0; k < 8; ++k) {
            int hv = hist[tid * 8 + k];
            l[k] = (hv < CELL) ? hv : CELL;
            s += l[k];
        }
        int inc = s;
        #pragma unroll
        for (int dd = 1; dd < 64; dd <<= 1) {
            int tt = __shfl_up(inc, dd, 64);
            if (tid >= dd) inc += tt;
        }
        int run = inc - s;
        #pragma unroll
        for (int k = 0; k < 8; ++k) {
            off[tid * 8 + k] = run;
            run += l[k];
        }
        if (tid == 63) off[512] = run;
    }
    __syncthreads();

    // scatter into LDS sorted[]
    #pragma unroll
    for (int i = 0; i < EPT; ++i) {
        if (r[i] < 0) continue;
        int d = r[i] >> 8;
        if (rk[i] < CELL) {
            int2 q;
            q.x = ((r[i] & 255) << 17) | c[i];   // c < 2^17, row&255 in 17..24
            q.y = __float_as_int(v[i]);
            sorted[off[d] + rk[i]] = q;
        } else {
            int o = atomicAdd(ovf_count, 1);  // far, rare (~1e3 edges)
            if (o < OVF_CAP) {
                int4 q;
                q.x = r[i]; q.y = c[i]; q.z = __float_as_int(v[i]); q.w = 0;
                ovf[o] = q;
            }
        }
    }
    __syncthreads();

    // coalesced writeout: consecutive lanes -> consecutive slots -> runs of
    // consecutive global addresses within each (d,b) cell.
    int tot = off[512];
    for (int s = tid; s < tot; s += 1024) {
        // binary search: largest d with off[d] <= s
        int lo = 0, hi = 512;
        while (hi - lo > 1) {
            int mid = (lo + hi) >> 1;
            if (off[mid] <= s) lo = mid; else hi = mid;
        }
        int2 q = sorted[s];
        coarse[((size_t)lo * NBLK + b) * CELL + (s - off[lo])] = q;
    }
    for (int d = tid; d < ND; d += 1024) {
        int h = hist[d];
        cellcnt[(size_t)d * NBLK + b] = (h < CELL) ? h : CELL;
    }
}

// ====== fused bucket CSR gather (R11 verbatim, measured 72.6us) ======
// One block per 256-row bucket d. 1024 threads.
//  S1: per-lane coalesced read of bucket's coarse cells, LDS int atomic rank.
//  S2: 64-lane shuffle prefix-scan of cnt[256] -> off[257].
//  S3: scatter (col,val) entries into LDS csr[off[r]+rank].
//  S4: 64 groups x 16 lanes; group handles 4 rows; per row read (col,val)
//      by LDS broadcast, 8 independent half8 (16B) supporth loads per lane,
//      fp32 accumulate (2 rotating sets), coalesced nontemporal stores.

__global__ __launch_bounds__(1024) void
bucket_csr_gather_kernel(const half8v* __restrict__ supporth,
                         const int2* __restrict__ coarse,
                         const int* __restrict__ cellcnt,
                         float4* __restrict__ out4,
                         int NBLK, int N) {
    __shared__ int  cnt[BROWS + 1];
    __shared__ int  off[BROWS + 1];
    __shared__ int2 csr[MAXSLOT + 8];   // +8 pad: gather reads up to end-1+7

    const int d   = blockIdx.x;
    const int tid = threadIdx.x;
    const int2* cbase = coarse  + (size_t)d * NBLK * CELL;
    const int*  ccnt  = cellcnt + (size_t)d * NBLK;
    const int total = NBLK * CELL;

    if (tid < BROWS + 1) cnt[tid] = 0;
    __syncthreads();

    // ---- S1: load + rank ----
    int2 ent[MAXIT];
    int  err[MAXIT];
    int  ernk[MAXIT];
    #pragma unroll
    for (int it = 0; it < MAXIT; ++it) {
        int s = tid + it * 1024;
        err[it] = -1;
        if (s < total && (s & (CELL - 1)) < ccnt[s >> 5]) {   // CELL == 32
            int2 q = cbase[s];
            int r = (q.x >> 17) & 255;
            ent[it].x = q.x & 0x1FFFF;
            ent[it].y = q.y;
            err[it] = r;
            ernk[it] = atomicAdd(&cnt[r], 1);                 // LDS int rtn atomic
        }
    }
    __syncthreads();

    // ---- S2: prefix scan cnt[256] -> off (wave 0 only) ----
    if (tid < 64) {
        int4 c4 = ((int4*)cnt)[tid];
        int t0 = c4.x;
        int t1 = t0 + c4.y;
        int t2 = t1 + c4.z;
        int t3 = t2 + c4.w;
        int inc = t3;
        #pragma unroll
        for (int dd = 1; dd < 64; dd <<= 1) {
            int t = __shfl_up(inc, dd, 64);
            if (tid >= dd) inc += t;
        }
        int excl = inc - t3;
        off[tid * 4 + 0] = excl;
        off[tid * 4 + 1] = excl + t0;
        off[tid * 4 + 2] = excl + t1;
        off[tid * 4 + 3] = excl + t2;
        if (tid == 63) off[BROWS] = inc;
    }
    __syncthreads();

    // ---- S3: scatter into LDS CSR ----
    #pragma unroll
    for (int it = 0; it < MAXIT; ++it) {
        if (err[it] >= 0)
            csr[off[err[it]] + ernk[it]] = ent[it];
    }
    __syncthreads();

    // ---- S4: gather, 16-lane groups, half8 loads ----
    const int g = tid >> 4;       // group 0..63
    const int i = tid & 15;       // lane in group; feats 8i..8i+7
    const int base = d << 8;
    for (int rq = 0; rq < 4; ++rq) {
        int r   = (rq << 6) + g;            // 0..255
        int beg = off[r];
        int end = off[r + 1];
        vfloat4 a00 = {0.f,0.f,0.f,0.f}, a01 = {0.f,0.f,0.f,0.f};
        vfloat4 a10 = {0.f,0.f,0.f,0.f}, a11 = {0.f,0.f,0.f,0.f};
        for (int k0 = beg; k0 < end; k0 += 8) {
            int   cc[8];
            float vv[8];
            #pragma unroll
            for (int u = 0; u < 8; ++u) {
                int2 e = csr[k0 + u];       // LDS broadcast (uniform per group)
                bool ib = (k0 + u) < end;
                cc[u] = ib ? e.x : 0;
                vv[u] = ib ? __int_as_float(e.y) : 0.f;
            }
            half8v s[8];
            #pragma unroll
            for (int u = 0; u < 8; ++u)
                s[u] = supporth[(size_t)cc[u] * H8 + i];
            #pragma unroll
            for (int u = 0; u < 8; ++u) {
                float v = vv[u];
                if (u & 1) {
                    a10.x += v * (float)s[u][0];
                    a10.y += v * (float)s[u][1];
                    a10.z += v * (float)s[u][2];
                    a10.w += v * (float)s[u][3];
                    a11.x += v * (float)s[u][4];
                    a11.y += v * (float)s[u][5];
                    a11.z += v * (float)s[u][6];
                    a11.w += v * (float)s[u][7];
                } else {
                    a00.x += v * (float)s[u][0];
                    a00.y += v * (float)s[u][1];
                    a00.z += v * (float)s[u][2];
                    a00.w += v * (float)s[u][3];
                    a01.x += v * (float)s[u][4];
                    a01.y += v * (float)s[u][5];
                    a01.z += v * (float)s[u][6];
                    a01.w += v * (float)s[u][7];
                }
            }
        }
        int row = base + r;
        if (row < N) {
            vfloat4 r0, r1;
            r0.x = a00.x + a10.x; r0.y = a00.y + a10.y;
            r0.z = a00.z + a10.z; r0.w = a00.w + a10.w;
            r1.x = a01.x + a11.x; r1.y = a01.y + a11.y;
            r1.z = a01.z + a11.z; r1.w = a01.w + a11.w;
            float4* dst = &out4[(size_t)row * F4 + (i << 1)];
            __builtin_nontemporal_store(r0, (vfloat4*)dst);
            __builtin_nontemporal_store(r1, (vfloat4*)(dst + 1));
        }
    }
}

// ============ overflow cleanup (after gather; adds onto its output) ============

__global__ void ovf_scatter_kernel(const float* __restrict__ support,
                                   const int4* __restrict__ ovf,
                                   const int* __restrict__ ovf_count,
                                   float* __restrict__ out, int cap) {
    int gid = blockIdx.x * blockDim.x + threadIdx.x;
    int i = gid >> 5;
    int j = gid & 31;
    int istride = (gridDim.x * blockDim.x) >> 5;
    int cnt = *ovf_count;
    if (cnt > cap) cnt = cap;
    for (; i < cnt; i += istride) {
        int4 q = ovf[i];
        float v = __int_as_float(q.z);
        const float4* s4 = (const float4*)support + (size_t)q.y * F4 + j;
        float4 s = *s4;
        float* o = out + (size_t)q.x * D_FEAT + j * 4;
        unsafeAtomicAdd(o + 0, v * s.x);
        unsafeAtomicAdd(o + 1, v * s.y);
        unsafeAtomicAdd(o + 2, v * s.z);
        unsafeAtomicAdd(o + 3, v * s.w);
    }
}

// ================= fallback 1: R5 fp16 path (device return-atomics) =================

__global__ void convert_kernel(const float4* __restrict__ in,
                               half8v* __restrict__ out, int n8) {
    int t = blockIdx.x * blockDim.x + threadIdx.x;
    if (t >= n8) return;
    float4 a = in[(size_t)t * 2];
    float4 b = in[(size_t)t * 2 + 1];
    half8v h;
    h[0] = (_Float16)a.x; h[1] = (_Float16)a.y;
    h[2] = (_Float16)a.z; h[3] = (_Float16)a.w;
    h[4] = (_Float16)b.x; h[5] = (_Float16)b.y;
    h[6] = (_Float16)b.z; h[7] = (_Float16)b.w;
    out[t] = h;
}

__global__ void gather_half_kernel(const half4v* __restrict__ supporth,
                                   const int* __restrict__ cursor,
                                   const int2* __restrict__ pairs,
                                   float4* __restrict__ out4, int n_nodes) {
    unsigned int t = blockIdx.x * blockDim.x + threadIdx.x;
    unsigned int row = t >> 5;
    unsigned int j = t & 31;
    if (row >= (unsigned int)n_nodes) return;
    int deg = cursor[row];
    if (deg > STRIDE) deg = STRIDE;
    const int2* pr = pairs + (size_t)row * STRIDE;
    int2 z = {0, 0};
    int2 p0 = ((int)j < deg) ? pr[j] : z;
    int2 p1 = ((int)(j + 32) < deg) ? pr[j + 32] : z;
    int   c0 = p0.x;  float v0 = __int_as_float(p0.y);
    int   c1 = p1.x;  float v1 = __int_as_float(p1.y);
    int degr = (deg + 7) & ~7;
    float4 acc[4];
    #pragma unroll
    for (int u = 0; u < 4; ++u) acc[u] = {0.f, 0.f, 0.f, 0.f};
    for (int k = 0; k < degr; k += 8) {
        int   cc[8];
        float vv[8];
        #pragma unroll
        for (int u = 0; u < 8; ++u) {
            int kk = k + u;
            cc[u] = __shfl(kk < 32 ? c0 : c1, kk & 31, 32);
            vv[u] = __shfl(kk < 32 ? v0 : v1, kk & 31, 32);
        }
        half4v s[8];
        #pragma unroll
        for (int u = 0; u < 8; ++u)
            s[u] = supporth[(size_t)cc[u] * H4 + j];
        #pragma unroll
        for (int u = 0; u < 8; ++u) {
            acc[u & 3].x += vv[u] * (float)s[u][0];
            acc[u & 3].y += vv[u] * (float)s[u][1];
            acc[u & 3].z += vv[u] * (float)s[u][2];
            acc[u & 3].w += vv[u] * (float)s[u][3];
        }
    }
    vfloat4 res;
    res.x = (acc[0].x + acc[1].x) + (acc[2].x + acc[3].x);
    res.y = (acc[0].y + acc[1].y) + (acc[2].y + acc[3].y);
    res.z = (acc[0].z + acc[1].z) + (acc[2].z + acc[3].z);
    res.w = (acc[0].w + acc[1].w) + (acc[2].w + acc[3].w);
    __builtin_nontemporal_store(res, (vfloat4*)&out4[(size_t)row * F4 + j]);
}

__global__ void bucket_ilp_kernel(const int* __restrict__ rows,
                                  const int* __restrict__ cols,
                                  const float* __restrict__ vals,
                                  int* __restrict__ cursor,
                                  int* __restrict__ ovf_count,
                                  int2* __restrict__ pairs,
                                  int4* __restrict__ ovf,
                                  int n_edges, int gstride) {
    int tid = blockIdx.x * blockDim.x + threadIdx.x;
    int   r[EPT];
    int   c[EPT];
    float v[EPT];
    int   slot[EPT];
    #pragma unroll
    for (int i = 0; i < EPT; ++i) {
        int e = tid + i * gstride;
        r[i] = (e < n_edges) ? rows[e] : -1;
    }
    #pragma unroll
    for (int i = 0; i < EPT; ++i) {
        int e = tid + i * gstride;
        if (e < n_edges) { c[i] = cols[e]; v[i] = vals[e]; }
    }
    #pragma unroll
    for (int i = 0; i < EPT; ++i)
        slot[i] = (r[i] >= 0) ? atomicAdd(&cursor[r[i]], 1) : 0;
    #pragma unroll
    for (int i = 0; i < EPT; ++i) {
        if (r[i] < 0) continue;
        int2 p;
        p.x = c[i];
        p.y = __float_as_int(v[i]);
        if (slot[i] < STRIDE) {
            pairs[(size_t)r[i] * STRIDE + slot[i]] = p;
        } else {
            int o = atomicAdd(ovf_count, 1);
            if (o < OVF_CAP) {
                int4 q; q.x = r[i]; q.y = p.x; q.z = p.y; q.w = 0;
                ovf[o] = q;
            }
        }
    }
}

// ==================== fallback 2: atomic scatter (R0) ====================

__global__ void gc_scatter_kernel(const float* __restrict__ support,
                                  const float* __restrict__ vals,
                                  const int* __restrict__ rows,
                                  const int* __restrict__ cols,
                                  float* __restrict__ out, int n_edges) {
    unsigned int t = blockIdx.x * blockDim.x + threadIdx.x;
    unsigned int e = t >> 5;
    unsigned int j = t & 31;
    if (e >= (unsigned int)n_edges) return;
    int r = rows[e];
    int c = cols[e];
    float v = vals[e];
    const float4* s4 = reinterpret_cast<const float4*>(support) + (size_t)c * F4 + j;
    float4 s = *s4;
    float* o = out + (size_t)r * D_FEAT + j * 4;
    unsafeAtomicAdd(o + 0, v * s.x);
    unsafeAtomicAdd(o + 1, v * s.y);
    unsafeAtomicAdd(o + 2, v * s.z);
    unsafeAtomicAdd(o + 3, v * s.w);
}

// ============================ launch ============================

extern "C" void kernel_launch(void* const* d_in, const int* in_sizes, int n_in,
                              void* d_out, int out_size, void* d_ws, size_t ws_size,
                              hipStream_t stream) {
    const float* support = (const float*)d_in[0];
    const float* vals    = (const float*)d_in[1];
    const int*   rows    = (const int*)d_in[2];
    const int*   cols    = (const int*)d_in[3];
    float* out = (float*)d_out;

    int E = in_sizes[1];
    int N = in_sizes[0] / D_FEAT;
    int n8 = N * D_FEAT / 8;
    int ND = (N + BROWS - 1) / BROWS;             // 256-row buckets (391)
    int NBLK = (E + 1024 * EPT - 1) / (1024 * EPT);  // bin blocks (196)
    int BT = NBLK * 1024;

    char* ws = (char*)d_ws;
    size_t cur = 0;
    auto carve = [&](size_t bytes) -> void* {
        void* p = ws + cur;
        cur += (bytes + 255) & ~(size_t)255;
        return p;
    };

    // ---- primary: LDS counting-sort binning + fused LDS-CSR bucket gather ----
    {
        size_t save = cur;
        int2*   coarse    = (int2*)carve((size_t)ND * NBLK * CELL * 8);
        int*    cellcnt   = (int*)carve((size_t)ND * NBLK * 4);
        int4*   ovf       = (int4*)carve((size_t)OVF_CAP * 16);
        int*    ovf_count = (int*)carve(256);
        half8v* supporth  = (half8v*)carve((size_t)N * D_FEAT * 2);
        if (cur <= ws_size && ND <= 512 && NBLK * CELL <= MAXSLOT) {
            (void)hipMemsetAsync(ovf_count, 0, 4, stream);
            int cblocks = (n8 + 1023) / 1024;
            phase1_bin_kernel<<<NBLK + cblocks, 1024, 0, stream>>>(
                (const float4*)support, supporth, rows, cols, vals,
                coarse, cellcnt, ovf, ovf_count, E, BT, NBLK, ND, n8);
            bucket_csr_gather_kernel<<<ND, 1024, 0, stream>>>(
                supporth, coarse, cellcnt, (float4*)out, NBLK, N);
            ovf_scatter_kernel<<<512, 256, 0, stream>>>(
                support, ovf, ovf_count, out, OVF_CAP);
            return;
        }
        cur = save;
    }

    // ---- fallback 1: R5 fp16 padded buckets (device return-atomics) ----
    {
        size_t save = cur;
        int*    cursor   = (int*)carve((size_t)(N + 1) * 4);
        int2*   pairs    = (int2*)carve((size_t)N * STRIDE * 8);
        int4*   ovf      = (int4*)carve((size_t)8192 * 16);
        half8v* supporth = (half8v*)carve((size_t)N * D_FEAT * 2);
        if (cur <= ws_size) {
            int* ovf_count = cursor + N;
            int bthreads = (E + EPT - 1) / EPT;
            int bblocks = (bthreads + 255) / 256;
            int gstride = bblocks * 256;
            (void)hipMemsetAsync(cursor, 0, (size_t)(N + 1) * 4, stream);
            convert_kernel<<<(n8 + 255) / 256, 256, 0, stream>>>(
                (const float4*)support, supporth, n8);
            bucket_ilp_kernel<<<bblocks, 256, 0, stream>>>(
                rows, cols, vals, cursor, ovf_count, pairs, ovf, E, gstride);
            unsigned int gthreads = (unsigned int)N * 32;
            gather_half_kernel<<<(gthreads + 255) / 256, 256, 0, stream>>>(
                (const half4v*)supporth, cursor, pairs, (float4*)out, N);
            ovf_scatter_kernel<<<512, 256, 0, stream>>>(
                support, ovf, ovf_count, out, 8192);
            return;
        }
        cur = save;
    }

    // ---- fallback 2: atomic scatter ----
    (void)hipMemsetAsync(d_out, 0, (size_t)out_size * sizeof(float), stream);
    unsigned int total = (unsigned int)E * 32;
    gc_scatter_kernel<<<(total + 255) / 256, 256, 0, stream>>>(
        support, vals, rows, cols, out, E);
}

// Round 7
// 187.818 us; speedup vs baseline: 1.4152x; 1.0819x over previous
//
#include <hip/hip_runtime.h>
#include <hip/hip_bf16.h>
#include <hip/hip_fp16.h>

// GraphConvolution: out = segment_sum(vals[:,None] * support[cols], rows)
// N=100000 nodes, E=1600000 edges, F=128 features, fp32.
//
// Round 14: R13 post-mortem — counting-sort phase1 neutral (203 ~ R10's 202);
//  gather is the measured lever: R7's standalone gather did the SAME 180MB
//  FETCH at 3.8 TB/s / 59% occupancy vs our 3.2 TB/s / 30%. Cause: 391
//  1024-thr blocks -> 2/CU thread-cap and 391/256=1.53 rounds -> ~30%
//  makespan waste. Fix: 500 buckets x 200 rows, 512 threads, ~35KB LDS ->
//  3 blocks/CU, single round. S1 goes TWO-PASS (count, scan, re-read+scatter
//  with second LDS counter) to keep VGPRs lean instead of 13-deep register
//  staging. CELL stays 32 (lambda=16.4 -> overflow ~100s, NOT R12's 12K).
//  phase1: R13 counting sort, d=row/200, 8-bit local row.

#define D_FEAT 128
#define F4 32            // float4s per feature vector
#define H4 32            // half4s per feature vector
#define H8 16            // half8s per feature vector
#define STRIDE 64        // padded slots per row (fallback 1 only)
#define CELL 32          // slots per (bucket, block) cell (Poisson(16.4))
#define OVF_CAP 131072   // overflow list capacity
#define EPT 8            // edges per thread in binning
#define MAXSLOT 3840     // LDS csr capacity (entries), ~ +11 sigma
#define BROWS 200        // rows per gather bucket
#define GT 512           // gather threads per block

typedef float    vfloat4 __attribute__((ext_vector_type(4)));
typedef _Float16 half4v  __attribute__((ext_vector_type(4)));
typedef _Float16 half8v  __attribute__((ext_vector_type(8)));

// ============ phase 1: LDS counting-sort bin + fused fp32->fp16 convert ============

__global__ __launch_bounds__(1024) void
phase1_bin_kernel(const float4* __restrict__ support4,
                  half8v* __restrict__ supporth,
                  const int* __restrict__ rows,
                  const int* __restrict__ cols,
                  const float* __restrict__ vals,
                  int2* __restrict__ coarse,     // [ND][NBLK][CELL] packed
                  int* __restrict__ cellcnt,     // [ND][NBLK]
                  int4* __restrict__ ovf,
                  int* __restrict__ ovf_count,
                  int E, int BT, int NBLK, int ND, int n8) {
    int b = blockIdx.x;
    int tid = threadIdx.x;

    if (b >= NBLK) {
        // -------- convert slice --------
        int m = (b - NBLK) * 1024 + tid;
        if (m < n8) {
            float4 a0 = support4[(size_t)m * 2];
            float4 a1 = support4[(size_t)m * 2 + 1];
            half8v h;
            h[0] = (_Float16)a0.x; h[1] = (_Float16)a0.y;
            h[2] = (_Float16)a0.z; h[3] = (_Float16)a0.w;
            h[4] = (_Float16)a1.x; h[5] = (_Float16)a1.y;
            h[6] = (_Float16)a1.z; h[7] = (_Float16)a1.w;
            supporth[m] = h;
        }
        return;
    }

    // -------- bin slice: counting sort in LDS, coalesced writeout --------
    __shared__ int  hist[512];
    __shared__ int  off[513];
    __shared__ int2 sorted[1024 * EPT];   // 64 KB

    for (int i = tid; i < 512; i += 1024) hist[i] = 0;
    __syncthreads();

    int t = b * 1024 + tid;
    int   r[EPT];
    int   c[EPT];
    float v[EPT];
    int   rk[EPT];

    #pragma unroll
    for (int i = 0; i < EPT; ++i) {
        int e = t + i * BT;
        r[i] = (e < E) ? rows[e] : -1;
    }
    #pragma unroll
    for (int i = 0; i < EPT; ++i) {
        int e = t + i * BT;
        if (e < E) { c[i] = cols[e]; v[i] = vals[e]; }
    }
    // LDS int return-atomics: native ds_add_rtn_u32
    #pragma unroll
    for (int i = 0; i < EPT; ++i)
        rk[i] = (r[i] >= 0) ? atomicAdd(&hist[r[i] / BROWS], 1) : 0;
    __syncthreads();

    // clamped prefix scan of 512 bins (wave 0; 8 bins/lane serial + wave scan)
    if (tid < 64) {
        int l[8];
        int s = 0;
        #pragma unroll
        for (int k = 0; k < 8; ++k) {
            int hv = hist[tid * 8 + k];
            l[k] = (hv < CELL) ? hv : CELL;
            s += l[k];
        }
        int inc = s;
        #pragma unroll
        for (int dd = 1; dd < 64; dd <<= 1) {
            int tt = __shfl_up(inc, dd, 64);
            if (tid >= dd) inc += tt;
        }
        int run = inc - s;
        #pragma unroll
        for (int k = 0; k < 8; ++k) {
            off[tid * 8 + k] = run;
            run += l[k];
        }
        if (tid == 63) off[512] = run;
    }
    __syncthreads();

    // scatter into LDS sorted[]
    #pragma unroll
    for (int i = 0; i < EPT; ++i) {
        if (r[i] < 0) continue;
        int d = r[i] / BROWS;
        if (rk[i] < CELL) {
            int2 q;
            q.x = ((r[i] - d * BROWS) << 17) | c[i];  // c < 2^17, local<200 in 17..24
            q.y = __float_as_int(v[i]);
            sorted[off[d] + rk[i]] = q;
        } else {
            int o = atomicAdd(ovf_count, 1);  // far, rare (~100s of edges)
            if (o < OVF_CAP) {
                int4 q;
                q.x = r[i]; q.y = c[i]; q.z = __float_as_int(v[i]); q.w = 0;
                ovf[o] = q;
            }
        }
    }
    __syncthreads();

    // coalesced writeout: consecutive lanes -> consecutive slots -> runs of
    // consecutive global addresses within each (d,b) cell.
    int tot = off[512];
    for (int s = tid; s < tot; s += 1024) {
        // binary search: largest d with off[d] <= s
        int lo = 0, hi = 512;
        while (hi - lo > 1) {
            int mid = (lo + hi) >> 1;
            if (off[mid] <= s) lo = mid; else hi = mid;
        }
        int2 q = sorted[s];
        coarse[((size_t)lo * NBLK + b) * CELL + (s - off[lo])] = q;
    }
    for (int d = tid; d < ND; d += 1024) {
        int h = hist[d];
        cellcnt[(size_t)d * NBLK + b] = (h < CELL) ? h : CELL;
    }
}

// ====== fused bucket CSR gather: two-pass rank + LDS CSR + half8 gather ======
// One block per 200-row bucket d. 512 threads, ~35KB LDS -> 3 blocks/CU.
//  A : preload cellcnt row; pass over coarse counting rows (LDS atomics).
//  S2: 64-lane shuffle prefix-scan of cnt[256-padded] -> off.
//  B : re-read coarse, rank via second counter, scatter into csr[off[r]+rk].
//  S4: 32 groups x 16 lanes; 7 row-iters; per row (col,val) by LDS broadcast,
//      8 independent half8 (16B) supporth loads per lane, dual fp32 acc,
//      coalesced nontemporal stores.

__global__ __launch_bounds__(GT) void
bucket_csr_gather_kernel(const half8v* __restrict__ supporth,
                         const int2* __restrict__ coarse,
                         const int* __restrict__ cellcnt,
                         float4* __restrict__ out4,
                         int NBLK, int N) {
    __shared__ int  cnt[257];
    __shared__ int  cnt2[257];
    __shared__ int  off[257];
    __shared__ int  ccl[256];           // cellcnt row (NBLK <= 256)
    __shared__ int2 csr[MAXSLOT + 8];   // +8 pad: gather reads up to end-1+7

    const int d   = blockIdx.x;
    const int tid = threadIdx.x;
    const int2* cbase = coarse + (size_t)d * NBLK * CELL;
    const int total = NBLK * CELL;

    if (tid < 257) { cnt[tid] = 0; cnt2[tid] = 0; }
    for (int i = tid; i < NBLK; i += GT)
        ccl[i] = cellcnt[(size_t)d * NBLK + i];
    __syncthreads();

    // ---- pass A: count rows ----
    for (int s = tid; s < total; s += GT) {
        if ((s & (CELL - 1)) < ccl[s >> 5]) {          // CELL == 32
            int rx = cbase[s].x;
            atomicAdd(&cnt[(rx >> 17) & 255], 1);
        }
    }
    __syncthreads();

    // ---- S2: prefix scan cnt[256] -> off (wave 0 only; bins >= BROWS are 0) ----
    if (tid < 64) {
        int4 c4 = ((int4*)cnt)[tid];
        int t0 = c4.x;
        int t1 = t0 + c4.y;
        int t2 = t1 + c4.z;
        int t3 = t2 + c4.w;
        int inc = t3;
        #pragma unroll
        for (int dd = 1; dd < 64; dd <<= 1) {
            int t = __shfl_up(inc, dd, 64);
            if (tid >= dd) inc += t;
        }
        int excl = inc - t3;
        off[tid * 4 + 0] = excl;
        off[tid * 4 + 1] = excl + t0;
        off[tid * 4 + 2] = excl + t1;
        off[tid * 4 + 3] = excl + t2;
        if (tid == 63) off[256] = inc;
    }
    __syncthreads();

    // ---- pass B: re-read, rank via cnt2, scatter into LDS CSR ----
    for (int s = tid; s < total; s += GT) {
        if ((s & (CELL - 1)) < ccl[s >> 5]) {
            int2 q = cbase[s];
            int r = (q.x >> 17) & 255;
            int rk = atomicAdd(&cnt2[r], 1);           // unique rank per row
            int2 e; e.x = q.x & 0x1FFFF; e.y = q.y;
            csr[off[r] + rk] = e;
        }
    }
    __syncthreads();

    // ---- S4: gather, 16-lane groups, half8 loads ----
    const int g = tid >> 4;       // group 0..31
    const int i = tid & 15;       // lane in group; feats 8i..8i+7
    const int base = d * BROWS;
    for (int rq = 0; rq < 7; ++rq) {
        int r = rq * 32 + g;                // 0..223; group-uniform guard
        if (r >= BROWS) continue;
        int beg = off[r];
        int end = off[r + 1];
        vfloat4 a00 = {0.f,0.f,0.f,0.f}, a01 = {0.f,0.f,0.f,0.f};
        vfloat4 a10 = {0.f,0.f,0.f,0.f}, a11 = {0.f,0.f,0.f,0.f};
        for (int k0 = beg; k0 < end; k0 += 8) {
            int   cc[8];
            float vv[8];
            #pragma unroll
            for (int u = 0; u < 8; ++u) {
                int2 e = csr[k0 + u];       // LDS broadcast (uniform per group)
                bool ib = (k0 + u) < end;
                cc[u] = ib ? e.x : 0;
                vv[u] = ib ? __int_as_float(e.y) : 0.f;
            }
            half8v s[8];
            #pragma unroll
            for (int u = 0; u < 8; ++u)
                s[u] = supporth[(size_t)cc[u] * H8 + i];
            #pragma unroll
            for (int u = 0; u < 8; ++u) {
                float v = vv[u];
                if (u & 1) {
                    a10.x += v * (float)s[u][0];
                    a10.y += v * (float)s[u][1];
                    a10.z += v * (float)s[u][2];
                    a10.w += v * (float)s[u][3];
                    a11.x += v * (float)s[u][4];
                    a11.y += v * (float)s[u][5];
                    a11.z += v * (float)s[u][6];
                    a11.w += v * (float)s[u][7];
                } else {
                    a00.x += v * (float)s[u][0];
                    a00.y += v * (float)s[u][1];
                    a00.z += v * (float)s[u][2];
                    a00.w += v * (float)s[u][3];
                    a01.x += v * (float)s[u][4];
                    a01.y += v * (float)s[u][5];
                    a01.z += v * (float)s[u][6];
                    a01.w += v * (float)s[u][7];
                }
            }
        }
        int row = base + r;
        if (row < N) {
            vfloat4 r0, r1;
            r0.x = a00.x + a10.x; r0.y = a00.y + a10.y;
            r0.z = a00.z + a10.z; r0.w = a00.w + a10.w;
            r1.x = a01.x + a11.x; r1.y = a01.y + a11.y;
            r1.z = a01.z + a11.z; r1.w = a01.w + a11.w;
            float4* dst = &out4[(size_t)row * F4 + (i << 1)];
            __builtin_nontemporal_store(r0, (vfloat4*)dst);
            __builtin_nontemporal_store(r1, (vfloat4*)(dst + 1));
        }
    }
}

// ============ overflow cleanup (after gather; adds onto its output) ============

__global__ void ovf_scatter_kernel(const float* __restrict__ support,
                                   const int4* __restrict__ ovf,
                                   const int* __restrict__ ovf_count,
                                   float* __restrict__ out, int cap) {
    int gid = blockIdx.x * blockDim.x + threadIdx.x;
    int i = gid >> 5;
    int j = gid & 31;
    int istride = (gridDim.x * blockDim.x) >> 5;
    int cnt = *ovf_count;
    if (cnt > cap) cnt = cap;
    for (; i < cnt; i += istride) {
        int4 q = ovf[i];
        float v = __int_as_float(q.z);
        const float4* s4 = (const float4*)support + (size_t)q.y * F4 + j;
        float4 s = *s4;
        float* o = out + (size_t)q.x * D_FEAT + j * 4;
        unsafeAtomicAdd(o + 0, v * s.x);
        unsafeAtomicAdd(o + 1, v * s.y);
        unsafeAtomicAdd(o + 2, v * s.z);
        unsafeAtomicAdd(o + 3, v * s.w);
    }
}

// ================= fallback 1: R5 fp16 path (device return-atomics) =================

__global__ void convert_kernel(const float4* __restrict__ in,
                               half8v* __restrict__ out, int n8) {
    int t = blockIdx.x * blockDim.x + threadIdx.x;
    if (t >= n8) return;
    float4 a = in[(size_t)t * 2];
    float4 b = in[(size_t)t * 2 + 1];
    half8v h;
    h[0] = (_Float16)a.x; h[1] = (_Float16)a.y;
    h[2] = (_Float16)a.z; h[3] = (_Float16)a.w;
    h[4] = (_Float16)b.x; h[5] = (_Float16)b.y;
    h[6] = (_Float16)b.z; h[7] = (_Float16)b.w;
    out[t] = h;
}

__global__ void gather_half_kernel(const half4v* __restrict__ supporth,
                                   const int* __restrict__ cursor,
                                   const int2* __restrict__ pairs,
                                   float4* __restrict__ out4, int n_nodes) {
    unsigned int t = blockIdx.x * blockDim.x + threadIdx.x;
    unsigned int row = t >> 5;
    unsigned int j = t & 31;
    if (row >= (unsigned int)n_nodes) return;
    int deg = cursor[row];
    if (deg > STRIDE) deg = STRIDE;
    const int2* pr = pairs + (size_t)row * STRIDE;
    int2 z = {0, 0};
    int2 p0 = ((int)j < deg) ? pr[j] : z;
    int2 p1 = ((int)(j + 32) < deg) ? pr[j + 32] : z;
    int   c0 = p0.x;  float v0 = __int_as_float(p0.y);
    int   c1 = p1.x;  float v1 = __int_as_float(p1.y);
    int degr = (deg + 7) & ~7;
    float4 acc[4];
    #pragma unroll
    for (int u = 0; u < 4; ++u) acc[u] = {0.f, 0.f, 0.f, 0.f};
    for (int k = 0; k < degr; k += 8) {
        int   cc[8];
        float vv[8];
        #pragma unroll
        for (int u = 0; u < 8; ++u) {
            int kk = k + u;
            cc[u] = __shfl(kk < 32 ? c0 : c1, kk & 31, 32);
            vv[u] = __shfl(kk < 32 ? v0 : v1, kk & 31, 32);
        }
        half4v s[8];
        #pragma unroll
        for (int u = 0; u < 8; ++u)
            s[u] = supporth[(size_t)cc[u] * H4 + j];
        #pragma unroll
        for (int u = 0; u < 8; ++u) {
            acc[u & 3].x += vv[u] * (float)s[u][0];
            acc[u & 3].y += vv[u] * (float)s[u][1];
            acc[u & 3].z += vv[u] * (float)s[u][2];
            acc[u & 3].w += vv[u] * (float)s[u][3];
        }
    }
    vfloat4 res;
    res.x = (acc[0].x + acc[1].x) + (acc[2].x + acc[3].x);
    res.y = (acc[0].y + acc[1].y) + (acc[2].y + acc[3].y);
    res.z = (acc[0].z + acc[1].z) + (acc[2].z + acc[3].z);
    res.w = (acc[0].w + acc[1].w) + (acc[2].w + acc[3].w);
    __builtin_nontemporal_store(res, (vfloat4*)&out4[(size_t)row * F4 + j]);
}

__global__ void bucket_ilp_kernel(const int* __restrict__ rows,
                                  const int* __restrict__ cols,
                                  const float* __restrict__ vals,
                                  int* __restrict__ cursor,
                                  int* __restrict__ ovf_count,
                                  int2* __restrict__ pairs,
                                  int4* __restrict__ ovf,
                                  int n_edges, int gstride) {
    int tid = blockIdx.x * blockDim.x + threadIdx.x;
    int   r[EPT];
    int   c[EPT];
    float v[EPT];
    int   slot[EPT];
    #pragma unroll
    for (int i = 0; i < EPT; ++i) {
        int e = tid + i * gstride;
        r[i] = (e < n_edges) ? rows[e] : -1;
    }
    #pragma unroll
    for (int i = 0; i < EPT; ++i) {
        int e = tid + i * gstride;
        if (e < n_edges) { c[i] = cols[e]; v[i] = vals[e]; }
    }
    #pragma unroll
    for (int i = 0; i < EPT; ++i)
        slot[i] = (r[i] >= 0) ? atomicAdd(&cursor[r[i]], 1) : 0;
    #pragma unroll
    for (int i = 0; i < EPT; ++i) {
        if (r[i] < 0) continue;
        int2 p;
        p.x = c[i];
        p.y = __float_as_int(v[i]);
        if (slot[i] < STRIDE) {
            pairs[(size_t)r[i] * STRIDE + slot[i]] = p;
        } else {
            int o = atomicAdd(ovf_count, 1);
            if (o < OVF_CAP) {
                int4 q; q.x = r[i]; q.y = p.x; q.z = p.y; q.w = 0;
                ovf[o] = q;
            }
        }
    }
}

// ==================== fallback 2: atomic scatter (R0) ====================

__global__ void gc_scatter_kernel(const float* __restrict__ support,
                                  const float* __restrict__ vals,
                                  const int* __restrict__ rows,
                                  const int* __restrict__ cols,
                                  float* __restrict__ out, int n_edges) {
    unsigned int t = blockIdx.x * blockDim.x + threadIdx.x;
    unsigned int e = t >> 5;
    unsigned int j = t & 31;
    if (e >= (unsigned int)n_edges) return;
    int r = rows[e];
    int c = cols[e];
    float v = vals[e];
    const float4* s4 = reinterpret_cast<const float4*>(support) + (size_t)c * F4 + j;
    float4 s = *s4;
    float* o = out + (size_t)r * D_FEAT + j * 4;
    unsafeAtomicAdd(o + 0, v * s.x);
    unsafeAtomicAdd(o + 1, v * s.y);
    unsafeAtomicAdd(o + 2, v * s.z);
    unsafeAtomicAdd(o + 3, v * s.w);
}

// ============================ launch ============================

extern "C" void kernel_launch(void* const* d_in, const int* in_sizes, int n_in,
                              void* d_out, int out_size, void* d_ws, size_t ws_size,
                              hipStream_t stream) {
    const float* support = (const float*)d_in[0];
    const float* vals    = (const float*)d_in[1];
    const int*   rows    = (const int*)d_in[2];
    const int*   cols    = (const int*)d_in[3];
    float* out = (float*)d_out;

    int E = in_sizes[1];
    int N = in_sizes[0] / D_FEAT;
    int n8 = N * D_FEAT / 8;
    int ND = (N + BROWS - 1) / BROWS;             // 200-row buckets (500)
    int NBLK = (E + 1024 * EPT - 1) / (1024 * EPT);  // bin blocks (196)
    int BT = NBLK * 1024;

    char* ws = (char*)d_ws;
    size_t cur = 0;
    auto carve = [&](size_t bytes) -> void* {
        void* p = ws + cur;
        cur += (bytes + 255) & ~(size_t)255;
        return p;
    };

    // ---- primary: LDS counting-sort binning + fused LDS-CSR bucket gather ----
    {
        size_t save = cur;
        int2*   coarse    = (int2*)carve((size_t)ND * NBLK * CELL * 8);
        int*    cellcnt   = (int*)carve((size_t)ND * NBLK * 4);
        int4*   ovf       = (int4*)carve((size_t)OVF_CAP * 16);
        int*    ovf_count = (int*)carve(256);
        half8v* supporth  = (half8v*)carve((size_t)N * D_FEAT * 2);
        if (cur <= ws_size && ND <= 512 && NBLK <= 256) {
            (void)hipMemsetAsync(ovf_count, 0, 4, stream);
            int cblocks = (n8 + 1023) / 1024;
            phase1_bin_kernel<<<NBLK + cblocks, 1024, 0, stream>>>(
                (const float4*)support, supporth, rows, cols, vals,
                coarse, cellcnt, ovf, ovf_count, E, BT, NBLK, ND, n8);
            bucket_csr_gather_kernel<<<ND, GT, 0, stream>>>(
                supporth, coarse, cellcnt, (float4*)out, NBLK, N);
            ovf_scatter_kernel<<<128, 256, 0, stream>>>(
                support, ovf, ovf_count, out, OVF_CAP);
            return;
        }
        cur = save;
    }

    // ---- fallback 1: R5 fp16 padded buckets (device return-atomics) ----
    {
        size_t save = cur;
        int*    cursor   = (int*)carve((size_t)(N + 1) * 4);
        int2*   pairs    = (int2*)carve((size_t)N * STRIDE * 8);
        int4*   ovf      = (int4*)carve((size_t)8192 * 16);
        half8v* supporth = (half8v*)carve((size_t)N * D_FEAT * 2);
        if (cur <= ws_size) {
            int* ovf_count = cursor + N;
            int bthreads = (E + EPT - 1) / EPT;
            int bblocks = (bthreads + 255) / 256;
            int gstride = bblocks * 256;
            (void)hipMemsetAsync(cursor, 0, (size_t)(N + 1) * 4, stream);
            convert_kernel<<<(n8 + 255) / 256, 256, 0, stream>>>(
                (const float4*)support, supporth, n8);
            bucket_ilp_kernel<<<bblocks, 256, 0, stream>>>(
                rows, cols, vals, cursor, ovf_count, pairs, ovf, E, gstride);
            unsigned int gthreads = (unsigned int)N * 32;
            gather_half_kernel<<<(gthreads + 255) / 256, 256, 0, stream>>>(
                (const half4v*)supporth, cursor, pairs, (float4*)out, N);
            ovf_scatter_kernel<<<512, 256, 0, stream>>>(
                support, ovf, ovf_count, out, 8192);
            return;
        }
        cur = save;
    }

    // ---- fallback 2: atomic scatter ----
    (void)hipMemsetAsync(d_out, 0, (size_t)out_size * sizeof(float), stream);
    unsigned int total = (unsigned int)E * 32;
    gc_scatter_kernel<<<(total + 255) / 256, 256, 0, stream>>>(
        support, vals, rows, cols, out, E);
}

// Round 8
// 185.734 us; speedup vs baseline: 1.4311x; 1.0112x over previous
//
#include <hip/hip_runtime.h>
#include <hip/hip_bf16.h>
#include <hip/hip_fp16.h>

// GraphConvolution: out = segment_sum(vals[:,None] * support[cols], rows)
// N=100000 nodes, E=1600000 edges, F=128 features, fp32.
//
// Round 15: R14 post-mortem — gather at component floor (62us R7 core + 9us
//  CSR prologue); occupancy capped by grid (500 blks ~ 2/CU), not residency.
//  phase1 ~50-55us vs ~20us BW floor is the big soft target. Changes:
//   1. phase1 writeout: replace per-slot 9-step binary search (9 DEPENDENT
//      LDS reads, serial) with 16-lane-group per-bucket copy -> 128B-run
//      coalesced stores, zero dependent reads. (R13 neutrality = search cost
//      ~= old scatter amplification; this keeps the fix, drops the cost.)
//   2. gather: one-pass register staging (R11's proven S1, 512thr x 13it)
//      instead of two-pass count+rescan; saves a coarse re-read (~12.5MB),
//      one LDS-atomic round, and guard evals. csr store bounds-guarded.
//  Geometry unchanged: 500 x 200-row buckets, CELL=32, counting-sort bin.

#define D_FEAT 128
#define F4 32            // float4s per feature vector
#define H4 32            // half4s per feature vector
#define H8 16            // half8s per feature vector
#define STRIDE 64        // padded slots per row (fallback 1 only)
#define CELL 32          // slots per (bucket, block) cell (Poisson(16.4))
#define OVF_CAP 131072   // overflow list capacity
#define EPT 8            // edges per thread in binning
#define GMAXIT 13        // gather S1 iterations: 512*13=6656 >= NBLK*CELL=6272
#define MAXSLOT 3840     // LDS csr capacity (entries), ~ +11 sigma of 3200
#define BROWS 200        // rows per gather bucket
#define GT 512           // gather threads per block

typedef float    vfloat4 __attribute__((ext_vector_type(4)));
typedef _Float16 half4v  __attribute__((ext_vector_type(4)));
typedef _Float16 half8v  __attribute__((ext_vector_type(8)));

// ============ phase 1: LDS counting-sort bin + fused fp32->fp16 convert ============

__global__ __launch_bounds__(1024) void
phase1_bin_kernel(const float4* __restrict__ support4,
                  half8v* __restrict__ supporth,
                  const int* __restrict__ rows,
                  const int* __restrict__ cols,
                  const float* __restrict__ vals,
                  int2* __restrict__ coarse,     // [ND][NBLK][CELL] packed
                  int* __restrict__ cellcnt,     // [ND][NBLK]
                  int4* __restrict__ ovf,
                  int* __restrict__ ovf_count,
                  int E, int BT, int NBLK, int ND, int n8) {
    int b = blockIdx.x;
    int tid = threadIdx.x;

    if (b >= NBLK) {
        // -------- convert slice --------
        int m = (b - NBLK) * 1024 + tid;
        if (m < n8) {
            float4 a0 = support4[(size_t)m * 2];
            float4 a1 = support4[(size_t)m * 2 + 1];
            half8v h;
            h[0] = (_Float16)a0.x; h[1] = (_Float16)a0.y;
            h[2] = (_Float16)a0.z; h[3] = (_Float16)a0.w;
            h[4] = (_Float16)a1.x; h[5] = (_Float16)a1.y;
            h[6] = (_Float16)a1.z; h[7] = (_Float16)a1.w;
            supporth[m] = h;
        }
        return;
    }

    // -------- bin slice: counting sort in LDS, coalesced writeout --------
    __shared__ int  hist[512];
    __shared__ int  off[513];
    __shared__ int2 sorted[1024 * EPT];   // 64 KB

    for (int i = tid; i < 512; i += 1024) hist[i] = 0;
    __syncthreads();

    int t = b * 1024 + tid;
    int   r[EPT];
    int   c[EPT];
    float v[EPT];
    int   rk[EPT];

    #pragma unroll
    for (int i = 0; i < EPT; ++i) {
        int e = t + i * BT;
        r[i] = (e < E) ? rows[e] : -1;
    }
    #pragma unroll
    for (int i = 0; i < EPT; ++i) {
        int e = t + i * BT;
        if (e < E) { c[i] = cols[e]; v[i] = vals[e]; }
    }
    // LDS int return-atomics: native ds_add_rtn_u32
    #pragma unroll
    for (int i = 0; i < EPT; ++i)
        rk[i] = (r[i] >= 0) ? atomicAdd(&hist[r[i] / BROWS], 1) : 0;
    __syncthreads();

    // clamped prefix scan of 512 bins (wave 0; 8 bins/lane serial + wave scan)
    if (tid < 64) {
        int l[8];
        int s = 0;
        #pragma unroll
        for (int k = 0; k < 8; ++k) {
            int hv = hist[tid * 8 + k];
            l[k] = (hv < CELL) ? hv : CELL;
            s += l[k];
        }
        int inc = s;
        #pragma unroll
        for (int dd = 1; dd < 64; dd <<= 1) {
            int tt = __shfl_up(inc, dd, 64);
            if (tid >= dd) inc += tt;
        }
        int run = inc - s;
        #pragma unroll
        for (int k = 0; k < 8; ++k) {
            off[tid * 8 + k] = run;
            run += l[k];
        }
        if (tid == 63) off[512] = run;
    }
    __syncthreads();

    // scatter into LDS sorted[]
    #pragma unroll
    for (int i = 0; i < EPT; ++i) {
        if (r[i] < 0) continue;
        int d = r[i] / BROWS;
        if (rk[i] < CELL) {
            int2 q;
            q.x = ((r[i] - d * BROWS) << 17) | c[i];  // c < 2^17, local<200 in 17..24
            q.y = __float_as_int(v[i]);
            sorted[off[d] + rk[i]] = q;
        } else {
            int o = atomicAdd(ovf_count, 1);  // far, rare (~100s of edges)
            if (o < OVF_CAP) {
                int4 q;
                q.x = r[i]; q.y = c[i]; q.z = __float_as_int(v[i]); q.w = 0;
                ovf[o] = q;
            }
        }
    }
    __syncthreads();

    // writeout: 16-lane group per bucket; no binary search, no dependent
    // chains; wave stores land as 4 x 128B coalesced runs.
    {
        int grp  = tid >> 4;     // 0..63
        int lane = tid & 15;
        for (int d = grp; d < 512; d += 64) {
            int o = off[d];
            int l = off[d + 1] - o;
            size_t gbase = ((size_t)d * NBLK + b) * CELL;
            for (int k = lane; k < l; k += 16)
                coarse[gbase + k] = sorted[o + k];
        }
    }
    for (int d = tid; d < ND; d += 1024) {
        int h = hist[d];
        cellcnt[(size_t)d * NBLK + b] = (h < CELL) ? h : CELL;
    }
}

// ====== fused bucket CSR gather: one-pass reg-staged rank + LDS CSR + half8 gather ======
// One block per 200-row bucket d. 512 threads, ~35KB LDS.
//  S1: single pass over bucket's coarse cells into registers (13 iters),
//      rank via LDS int return-atomic on cnt[row].
//  S2: 64-lane shuffle prefix-scan of cnt[256-padded] -> off.
//  S3: scatter staged entries into csr[off[r]+rk] (bounds-guarded).
//  S4: 32 groups x 16 lanes; 7 row-iters; per row (col,val) by LDS broadcast,
//      8 independent half8 (16B) supporth loads per lane, dual fp32 acc,
//      coalesced nontemporal stores.

__global__ __launch_bounds__(GT) void
bucket_csr_gather_kernel(const half8v* __restrict__ supporth,
                         const int2* __restrict__ coarse,
                         const int* __restrict__ cellcnt,
                         float4* __restrict__ out4,
                         int NBLK, int N) {
    __shared__ int  cnt[257];
    __shared__ int  off[257];
    __shared__ int  ccl[256];           // cellcnt row (NBLK <= 256)
    __shared__ int2 csr[MAXSLOT + 8];   // +8 pad: gather reads up to end-1+7

    const int d   = blockIdx.x;
    const int tid = threadIdx.x;
    const int2* cbase = coarse + (size_t)d * NBLK * CELL;
    const int total = NBLK * CELL;

    if (tid < 257) cnt[tid] = 0;
    for (int i = tid; i < NBLK; i += GT)
        ccl[i] = cellcnt[(size_t)d * NBLK + i];
    __syncthreads();

    // ---- S1: one-pass load + rank into registers ----
    int2 ent[GMAXIT];
    int  err[GMAXIT];
    int  ernk[GMAXIT];
    #pragma unroll
    for (int it = 0; it < GMAXIT; ++it) {
        int s = tid + it * GT;
        err[it] = -1;
        if (s < total && (s & (CELL - 1)) < ccl[s >> 5]) {   // CELL == 32
            int2 q = cbase[s];
            int r = (q.x >> 17) & 255;
            ent[it].x = q.x & 0x1FFFF;
            ent[it].y = q.y;
            err[it] = r;
            ernk[it] = atomicAdd(&cnt[r], 1);                // LDS int rtn atomic
        }
    }
    __syncthreads();

    // ---- S2: prefix scan cnt[256] -> off (wave 0 only; bins >= BROWS are 0) ----
    if (tid < 64) {
        int4 c4 = ((int4*)cnt)[tid];
        int t0 = c4.x;
        int t1 = t0 + c4.y;
        int t2 = t1 + c4.z;
        int t3 = t2 + c4.w;
        int inc = t3;
        #pragma unroll
        for (int dd = 1; dd < 64; dd <<= 1) {
            int t = __shfl_up(inc, dd, 64);
            if (tid >= dd) inc += t;
        }
        int excl = inc - t3;
        off[tid * 4 + 0] = excl;
        off[tid * 4 + 1] = excl + t0;
        off[tid * 4 + 2] = excl + t1;
        off[tid * 4 + 3] = excl + t2;
        if (tid == 63) off[256] = inc;
    }
    __syncthreads();

    // ---- S3: scatter into LDS CSR (bounds-guarded) ----
    #pragma unroll
    for (int it = 0; it < GMAXIT; ++it) {
        if (err[it] >= 0) {
            int idx = off[err[it]] + ernk[it];
            if (idx < MAXSLOT + 8) csr[idx] = ent[it];
        }
    }
    __syncthreads();

    // ---- S4: gather, 16-lane groups, half8 loads ----
    const int g = tid >> 4;       // group 0..31
    const int i = tid & 15;       // lane in group; feats 8i..8i+7
    const int base = d * BROWS;
    for (int rq = 0; rq < 7; ++rq) {
        int r = rq * 32 + g;                // 0..223; group-uniform guard
        if (r >= BROWS) continue;
        int beg = off[r];
        int end = off[r + 1];
        vfloat4 a00 = {0.f,0.f,0.f,0.f}, a01 = {0.f,0.f,0.f,0.f};
        vfloat4 a10 = {0.f,0.f,0.f,0.f}, a11 = {0.f,0.f,0.f,0.f};
        for (int k0 = beg; k0 < end; k0 += 8) {
            int   cc[8];
            float vv[8];
            #pragma unroll
            for (int u = 0; u < 8; ++u) {
                int2 e = csr[k0 + u];       // LDS broadcast (uniform per group)
                bool ib = (k0 + u) < end;
                cc[u] = ib ? e.x : 0;
                vv[u] = ib ? __int_as_float(e.y) : 0.f;
            }
            half8v s[8];
            #pragma unroll
            for (int u = 0; u < 8; ++u)
                s[u] = supporth[(size_t)cc[u] * H8 + i];
            #pragma unroll
            for (int u = 0; u < 8; ++u) {
                float v = vv[u];
                if (u & 1) {
                    a10.x += v * (float)s[u][0];
                    a10.y += v * (float)s[u][1];
                    a10.z += v * (float)s[u][2];
                    a10.w += v * (float)s[u][3];
                    a11.x += v * (float)s[u][4];
                    a11.y += v * (float)s[u][5];
                    a11.z += v * (float)s[u][6];
                    a11.w += v * (float)s[u][7];
                } else {
                    a00.x += v * (float)s[u][0];
                    a00.y += v * (float)s[u][1];
                    a00.z += v * (float)s[u][2];
                    a00.w += v * (float)s[u][3];
                    a01.x += v * (float)s[u][4];
                    a01.y += v * (float)s[u][5];
                    a01.z += v * (float)s[u][6];
                    a01.w += v * (float)s[u][7];
                }
            }
        }
        int row = base + r;
        if (row < N) {
            vfloat4 r0, r1;
            r0.x = a00.x + a10.x; r0.y = a00.y + a10.y;
            r0.z = a00.z + a10.z; r0.w = a00.w + a10.w;
            r1.x = a01.x + a11.x; r1.y = a01.y + a11.y;
            r1.z = a01.z + a11.z; r1.w = a01.w + a11.w;
            float4* dst = &out4[(size_t)row * F4 + (i << 1)];
            __builtin_nontemporal_store(r0, (vfloat4*)dst);
            __builtin_nontemporal_store(r1, (vfloat4*)(dst + 1));
        }
    }
}

// ============ overflow cleanup (after gather; adds onto its output) ============

__global__ void ovf_scatter_kernel(const float* __restrict__ support,
                                   const int4* __restrict__ ovf,
                                   const int* __restrict__ ovf_count,
                                   float* __restrict__ out, int cap) {
    int gid = blockIdx.x * blockDim.x + threadIdx.x;
    int i = gid >> 5;
    int j = gid & 31;
    int istride = (gridDim.x * blockDim.x) >> 5;
    int cnt = *ovf_count;
    if (cnt > cap) cnt = cap;
    for (; i < cnt; i += istride) {
        int4 q = ovf[i];
        float v = __int_as_float(q.z);
        const float4* s4 = (const float4*)support + (size_t)q.y * F4 + j;
        float4 s = *s4;
        float* o = out + (size_t)q.x * D_FEAT + j * 4;
        unsafeAtomicAdd(o + 0, v * s.x);
        unsafeAtomicAdd(o + 1, v * s.y);
        unsafeAtomicAdd(o + 2, v * s.z);
        unsafeAtomicAdd(o + 3, v * s.w);
    }
}

// ================= fallback 1: R5 fp16 path (device return-atomics) =================

__global__ void convert_kernel(const float4* __restrict__ in,
                               half8v* __restrict__ out, int n8) {
    int t = blockIdx.x * blockDim.x + threadIdx.x;
    if (t >= n8) return;
    float4 a = in[(size_t)t * 2];
    float4 b = in[(size_t)t * 2 + 1];
    half8v h;
    h[0] = (_Float16)a.x; h[1] = (_Float16)a.y;
    h[2] = (_Float16)a.z; h[3] = (_Float16)a.w;
    h[4] = (_Float16)b.x; h[5] = (_Float16)b.y;
    h[6] = (_Float16)b.z; h[7] = (_Float16)b.w;
    out[t] = h;
}

__global__ void gather_half_kernel(const half4v* __restrict__ supporth,
                                   const int* __restrict__ cursor,
                                   const int2* __restrict__ pairs,
                                   float4* __restrict__ out4, int n_nodes) {
    unsigned int t = blockIdx.x * blockDim.x + threadIdx.x;
    unsigned int row = t >> 5;
    unsigned int j = t & 31;
    if (row >= (unsigned int)n_nodes) return;
    int deg = cursor[row];
    if (deg > STRIDE) deg = STRIDE;
    const int2* pr = pairs + (size_t)row * STRIDE;
    int2 z = {0, 0};
    int2 p0 = ((int)j < deg) ? pr[j] : z;
    int2 p1 = ((int)(j + 32) < deg) ? pr[j + 32] : z;
    int   c0 = p0.x;  float v0 = __int_as_float(p0.y);
    int   c1 = p1.x;  float v1 = __int_as_float(p1.y);
    int degr = (deg + 7) & ~7;
    float4 acc[4];
    #pragma unroll
    for (int u = 0; u < 4; ++u) acc[u] = {0.f, 0.f, 0.f, 0.f};
    for (int k = 0; k < degr; k += 8) {
        int   cc[8];
        float vv[8];
        #pragma unroll
        for (int u = 0; u < 8; ++u) {
            int kk = k + u;
            cc[u] = __shfl(kk < 32 ? c0 : c1, kk & 31, 32);
            vv[u] = __shfl(kk < 32 ? v0 : v1, kk & 31, 32);
        }
        half4v s[8];
        #pragma unroll
        for (int u = 0; u < 8; ++u)
            s[u] = supporth[(size_t)cc[u] * H4 + j];
        #pragma unroll
        for (int u = 0; u < 8; ++u) {
            acc[u & 3].x += vv[u] * (float)s[u][0];
            acc[u & 3].y += vv[u] * (float)s[u][1];
            acc[u & 3].z += vv[u] * (float)s[u][2];
            acc[u & 3].w += vv[u] * (float)s[u][3];
        }
    }
    vfloat4 res;
    res.x = (acc[0].x + acc[1].x) + (acc[2].x + acc[3].x);
    res.y = (acc[0].y + acc[1].y) + (acc[2].y + acc[3].y);
    res.z = (acc[0].z + acc[1].z) + (acc[2].z + acc[3].z);
    res.w = (acc[0].w + acc[1].w) + (acc[2].w + acc[3].w);
    __builtin_nontemporal_store(res, (vfloat4*)&out4[(size_t)row * F4 + j]);
}

__global__ void bucket_ilp_kernel(const int* __restrict__ rows,
                                  const int* __restrict__ cols,
                                  const float* __restrict__ vals,
                                  int* __restrict__ cursor,
                                  int* __restrict__ ovf_count,
                                  int2* __restrict__ pairs,
                                  int4* __restrict__ ovf,
                                  int n_edges, int gstride) {
    int tid = blockIdx.x * blockDim.x + threadIdx.x;
    int   r[EPT];
    int   c[EPT];
    float v[EPT];
    int   slot[EPT];
    #pragma unroll
    for (int i = 0; i < EPT; ++i) {
        int e = tid + i * gstride;
        r[i] = (e < n_edges) ? rows[e] : -1;
    }
    #pragma unroll
    for (int i = 0; i < EPT; ++i) {
        int e = tid + i * gstride;
        if (e < n_edges) { c[i] = cols[e]; v[i] = vals[e]; }
    }
    #pragma unroll
    for (int i = 0; i < EPT; ++i)
        slot[i] = (r[i] >= 0) ? atomicAdd(&cursor[r[i]], 1) : 0;
    #pragma unroll
    for (int i = 0; i < EPT; ++i) {
        if (r[i] < 0) continue;
        int2 p;
        p.x = c[i];
        p.y = __float_as_int(v[i]);
        if (slot[i] < STRIDE) {
            pairs[(size_t)r[i] * STRIDE + slot[i]] = p;
        } else {
            int o = atomicAdd(ovf_count, 1);
            if (o < OVF_CAP) {
                int4 q; q.x = r[i]; q.y = p.x; q.z = p.y; q.w = 0;
                ovf[o] = q;
            }
        }
    }
}

// ==================== fallback 2: atomic scatter (R0) ====================

__global__ void gc_scatter_kernel(const float* __restrict__ support,
                                  const float* __restrict__ vals,
                                  const int* __restrict__ rows,
                                  const int* __restrict__ cols,
                                  float* __restrict__ out, int n_edges) {
    unsigned int t = blockIdx.x * blockDim.x + threadIdx.x;
    unsigned int e = t >> 5;
    unsigned int j = t & 31;
    if (e >= (unsigned int)n_edges) return;
    int r = rows[e];
    int c = cols[e];
    float v = vals[e];
    const float4* s4 = reinterpret_cast<const float4*>(support) + (size_t)c * F4 + j;
    float4 s = *s4;
    float* o = out + (size_t)r * D_FEAT + j * 4;
    unsafeAtomicAdd(o + 0, v * s.x);
    unsafeAtomicAdd(o + 1, v * s.y);
    unsafeAtomicAdd(o + 2, v * s.z);
    unsafeAtomicAdd(o + 3, v * s.w);
}

// ============================ launch ============================

extern "C" void kernel_launch(void* const* d_in, const int* in_sizes, int n_in,
                              void* d_out, int out_size, void* d_ws, size_t ws_size,
                              hipStream_t stream) {
    const float* support = (const float*)d_in[0];
    const float* vals    = (const float*)d_in[1];
    const int*   rows    = (const int*)d_in[2];
    const int*   cols    = (const int*)d_in[3];
    float* out = (float*)d_out;

    int E = in_sizes[1];
    int N = in_sizes[0] / D_FEAT;
    int n8 = N * D_FEAT / 8;
    int ND = (N + BROWS - 1) / BROWS;             // 200-row buckets (500)
    int NBLK = (E + 1024 * EPT - 1) / (1024 * EPT);  // bin blocks (196)
    int BT = NBLK * 1024;

    char* ws = (char*)d_ws;
    size_t cur = 0;
    auto carve = [&](size_t bytes) -> void* {
        void* p = ws + cur;
        cur += (bytes + 255) & ~(size_t)255;
        return p;
    };

    // ---- primary: LDS counting-sort binning + fused LDS-CSR bucket gather ----
    {
        size_t save = cur;
        int2*   coarse    = (int2*)carve((size_t)ND * NBLK * CELL * 8);
        int*    cellcnt   = (int*)carve((size_t)ND * NBLK * 4);
        int4*   ovf       = (int4*)carve((size_t)OVF_CAP * 16);
        int*    ovf_count = (int*)carve(256);
        half8v* supporth  = (half8v*)carve((size_t)N * D_FEAT * 2);
        if (cur <= ws_size && ND <= 512 && NBLK <= 256 && NBLK * CELL <= GT * GMAXIT) {
            (void)hipMemsetAsync(ovf_count, 0, 4, stream);
            int cblocks = (n8 + 1023) / 1024;
            phase1_bin_kernel<<<NBLK + cblocks, 1024, 0, stream>>>(
                (const float4*)support, supporth, rows, cols, vals,
                coarse, cellcnt, ovf, ovf_count, E, BT, NBLK, ND, n8);
            bucket_csr_gather_kernel<<<ND, GT, 0, stream>>>(
                supporth, coarse, cellcnt, (float4*)out, NBLK, N);
            ovf_scatter_kernel<<<128, 256, 0, stream>>>(
                support, ovf, ovf_count, out, OVF_CAP);
            return;
        }
        cur = save;
    }

    // ---- fallback 1: R5 fp16 padded buckets (device return-atomics) ----
    {
        size_t save = cur;
        int*    cursor   = (int*)carve((size_t)(N + 1) * 4);
        int2*   pairs    = (int2*)carve((size_t)N * STRIDE * 8);
        int4*   ovf      = (int4*)carve((size_t)8192 * 16);
        half8v* supporth = (half8v*)carve((size_t)N * D_FEAT * 2);
        if (cur <= ws_size) {
            int* ovf_count = cursor + N;
            int bthreads = (E + EPT - 1) / EPT;
            int bblocks = (bthreads + 255) / 256;
            int gstride = bblocks * 256;
            (void)hipMemsetAsync(cursor, 0, (size_t)(N + 1) * 4, stream);
            convert_kernel<<<(n8 + 255) / 256, 256, 0, stream>>>(
                (const float4*)support, supporth, n8);
            bucket_ilp_kernel<<<bblocks, 256, 0, stream>>>(
                rows, cols, vals, cursor, ovf_count, pairs, ovf, E, gstride);
            unsigned int gthreads = (unsigned int)N * 32;
            gather_half_kernel<<<(gthreads + 255) / 256, 256, 0, stream>>>(
                (const half4v*)supporth, cursor, pairs, (float4*)out, N);
            ovf_scatter_kernel<<<512, 256, 0, stream>>>(
                support, ovf, ovf_count, out, 8192);
            return;
        }
        cur = save;
    }

    // ---- fallback 2: atomic scatter ----
    (void)hipMemsetAsync(d_out, 0, (size_t)out_size * sizeof(float), stream);
    unsigned int total = (unsigned int)E * 32;
    gc_scatter_kernel<<<(total + 255) / 256, 256, 0, stream>>>(
        support, vals, rows, cols, out, E);
}

// Round 9
// 184.996 us; speedup vs baseline: 1.4368x; 1.0040x over previous
//
#include <hip/hip_runtime.h>
#include <hip/hip_bf16.h>
#include <hip/hip_fp16.h>

// GraphConvolution: out = segment_sum(vals[:,None] * support[cols], rows)
// N=100000 nodes, E=1600000 edges, F=128 features, fp32.
//
// Round 16: R15 post-mortem — three phase1 theories in a row were neutral;
//  untouched suspects are the padded per-cell coarse FORMAT (2x slot scan in
//  gather, clamp+pad in bin) and the bin grid (196x1024thr < 1 blk/CU, no
//  TLP to hide the LDS sort). This round replaces the format:
//  DENSE per-bucket lists. After the block-local counting sort, ONE global
//  return-atomic per (bucket,block) — 500 addrs x 391 blocks, ~400/addr,
//  all 500 issued in one parallel round per block — reserves a contiguous
//  range in dense[d*CAP..]; 16-lane groups copy sorted runs there.
//   - no CELL, no clamping, per-cell overflow GONE (only >=14-sigma bucket cap)
//   - bin blocks: 512 thr, EPT=8, 391 blocks, 39KB LDS -> 4/CU residency
//   - gather S1: scan exactly cnt[d] dense entries, scalar bound, no ccl[]
//  Gather core (S2..S4) and convert unchanged (proven).

#define D_FEAT 128
#define F4 32            // float4s per feature vector
#define H4 32            // half4s per feature vector
#define H8 16            // half8s per feature vector
#define STRIDE 64        // padded slots per row (fallback 1 only)
#define OVF_CAP 131072   // overflow list capacity
#define EPT 8            // edges per thread in binning
#define BINT 512         // bin threads per block
#define CAP 4096         // dense per-bucket capacity (lambda=3200, +14 sigma)
#define GMAXIT 8         // gather S1 iterations: 512*8 = 4096 = CAP
#define BROWS 200        // rows per gather bucket
#define GT 512           // gather threads per block

typedef float    vfloat4 __attribute__((ext_vector_type(4)));
typedef _Float16 half4v  __attribute__((ext_vector_type(4)));
typedef _Float16 half8v  __attribute__((ext_vector_type(8)));

// ============ phase 1: LDS counting-sort bin -> dense lists + fp32->fp16 convert ============

__global__ __launch_bounds__(BINT) void
phase1_bin_kernel(const float4* __restrict__ support4,
                  half8v* __restrict__ supporth,
                  const int* __restrict__ rows,
                  const int* __restrict__ cols,
                  const float* __restrict__ vals,
                  int2* __restrict__ dense,      // [ND][CAP] packed (lrow<<17|col, val)
                  int* __restrict__ gcur,        // [512] global bucket cursors (+[512]=ovf_count)
                  int4* __restrict__ ovf,
                  int* __restrict__ ovf_count,
                  int E, int BT, int NBLK, int n8) {
    int b = blockIdx.x;
    int tid = threadIdx.x;

    if (b >= NBLK) {
        // -------- convert slice --------
        int m = (b - NBLK) * BINT + tid;
        if (m < n8) {
            float4 a0 = support4[(size_t)m * 2];
            float4 a1 = support4[(size_t)m * 2 + 1];
            half8v h;
            h[0] = (_Float16)a0.x; h[1] = (_Float16)a0.y;
            h[2] = (_Float16)a0.z; h[3] = (_Float16)a0.w;
            h[4] = (_Float16)a1.x; h[5] = (_Float16)a1.y;
            h[6] = (_Float16)a1.z; h[7] = (_Float16)a1.w;
            supporth[m] = h;
        }
        return;
    }

    // -------- bin slice: counting sort in LDS, dense reservation writeout --------
    __shared__ int  hist[512];
    __shared__ int  off[513];
    __shared__ int  sstart[512];
    __shared__ int2 sorted[BINT * EPT];   // 32 KB

    for (int i = tid; i < 512; i += BINT) hist[i] = 0;
    __syncthreads();

    int t = b * BINT + tid;
    int   r[EPT];
    int   c[EPT];
    float v[EPT];
    int   rk[EPT];

    #pragma unroll
    for (int i = 0; i < EPT; ++i) {
        int e = t + i * BT;
        r[i] = (e < E) ? rows[e] : -1;
    }
    #pragma unroll
    for (int i = 0; i < EPT; ++i) {
        int e = t + i * BT;
        if (e < E) { c[i] = cols[e]; v[i] = vals[e]; }
    }
    // LDS int return-atomics: native ds_add_rtn_u32 (unclamped rank)
    #pragma unroll
    for (int i = 0; i < EPT; ++i)
        rk[i] = (r[i] >= 0) ? atomicAdd(&hist[r[i] / BROWS], 1) : 0;
    __syncthreads();

    // prefix scan of 512 bins (wave 0; 8 bins/lane serial + wave scan); no clamp
    if (tid < 64) {
        int l[8];
        int s = 0;
        #pragma unroll
        for (int k = 0; k < 8; ++k) {
            l[k] = hist[tid * 8 + k];
            s += l[k];
        }
        int inc = s;
        #pragma unroll
        for (int dd = 1; dd < 64; dd <<= 1) {
            int tt = __shfl_up(inc, dd, 64);
            if (tid >= dd) inc += tt;
        }
        int run = inc - s;
        #pragma unroll
        for (int k = 0; k < 8; ++k) {
            off[tid * 8 + k] = run;
            run += l[k];
        }
        if (tid == 63) off[512] = run;
    }
    __syncthreads();

    // scatter into LDS sorted[] (capacity exactly = edges in block)
    #pragma unroll
    for (int i = 0; i < EPT; ++i) {
        if (r[i] < 0) continue;
        int d = r[i] / BROWS;
        int2 q;
        q.x = ((r[i] - d * BROWS) << 17) | c[i];  // c < 2^17, local<200 in 17..24
        q.y = __float_as_int(v[i]);
        sorted[off[d] + rk[i]] = q;
    }
    __syncthreads();

    // one parallel round of per-bucket reservations (500 atomics, distinct threads)
    {
        int l = off[tid + 1] - off[tid];          // tid in [0,512)
        sstart[tid] = (l > 0) ? atomicAdd(&gcur[tid], l) : 0;
    }
    __syncthreads();

    // copy sorted runs into dense ranges; 16-lane group per bucket
    {
        int grp  = tid >> 4;     // 0..31
        int lane = tid & 15;
        for (int d = grp; d < 512; d += 32) {
            int o  = off[d];
            int l  = off[d + 1] - o;
            int st = sstart[d];
            for (int k = lane; k < l; k += 16) {
                int pos = st + k;
                int2 q = sorted[o + k];
                if (pos < CAP) {
                    dense[(size_t)d * CAP + pos] = q;
                } else {
                    int ox = atomicAdd(ovf_count, 1);   // ~never (>=14 sigma)
                    if (ox < OVF_CAP) {
                        int4 e4;
                        e4.x = d * BROWS + ((q.x >> 17) & 255);
                        e4.y = q.x & 0x1FFFF;
                        e4.z = q.y;
                        e4.w = 0;
                        ovf[ox] = e4;
                    }
                }
            }
        }
    }
}

// ====== fused bucket CSR gather: dense-list rank + LDS CSR + half8 gather ======
// One block per 200-row bucket d. 512 threads, ~36KB LDS.
//  S1: scan cnt[d] dense entries (8 iters), rank via LDS int return-atomic.
//  S2: 64-lane shuffle prefix-scan of cnt[256-padded] -> off.
//  S3: scatter staged entries into csr[off[r]+rk].
//  S4: 32 groups x 16 lanes; 7 row-iters; per row (col,val) by LDS broadcast,
//      8 independent half8 (16B) supporth loads per lane, dual fp32 acc,
//      coalesced nontemporal stores.

__global__ __launch_bounds__(GT) void
bucket_csr_gather_kernel(const half8v* __restrict__ supporth,
                         const int2* __restrict__ dense,
                         const int* __restrict__ gcur,
                         float4* __restrict__ out4, int N) {
    __shared__ int  cnt[257];
    __shared__ int  off[257];
    __shared__ int2 csr[CAP + 8];   // +8 pad: gather reads up to end-1+7

    const int d   = blockIdx.x;
    const int tid = threadIdx.x;
    const int2* dbase = dense + (size_t)d * CAP;

    int total = gcur[d];
    if (total > CAP) total = CAP;

    if (tid < 257) cnt[tid] = 0;
    __syncthreads();

    // ---- S1: one-pass load + rank into registers ----
    int2 ent[GMAXIT];
    int  err[GMAXIT];
    int  ernk[GMAXIT];
    #pragma unroll
    for (int it = 0; it < GMAXIT; ++it) {
        int s = tid + it * GT;
        err[it] = -1;
        if (s < total) {
            int2 q = dbase[s];
            int r = (q.x >> 17) & 255;
            ent[it].x = q.x & 0x1FFFF;
            ent[it].y = q.y;
            err[it] = r;
            ernk[it] = atomicAdd(&cnt[r], 1);                // LDS int rtn atomic
        }
    }
    __syncthreads();

    // ---- S2: prefix scan cnt[256] -> off (wave 0 only; bins >= BROWS are 0) ----
    if (tid < 64) {
        int4 c4 = ((int4*)cnt)[tid];
        int t0 = c4.x;
        int t1 = t0 + c4.y;
        int t2 = t1 + c4.z;
        int t3 = t2 + c4.w;
        int inc = t3;
        #pragma unroll
        for (int dd = 1; dd < 64; dd <<= 1) {
            int t = __shfl_up(inc, dd, 64);
            if (tid >= dd) inc += t;
        }
        int excl = inc - t3;
        off[tid * 4 + 0] = excl;
        off[tid * 4 + 1] = excl + t0;
        off[tid * 4 + 2] = excl + t1;
        off[tid * 4 + 3] = excl + t2;
        if (tid == 63) off[256] = inc;
    }
    __syncthreads();

    // ---- S3: scatter into LDS CSR ----
    #pragma unroll
    for (int it = 0; it < GMAXIT; ++it) {
        if (err[it] >= 0)
            csr[off[err[it]] + ernk[it]] = ent[it];
    }
    __syncthreads();

    // ---- S4: gather, 16-lane groups, half8 loads ----
    const int g = tid >> 4;       // group 0..31
    const int i = tid & 15;       // lane in group; feats 8i..8i+7
    const int base = d * BROWS;
    for (int rq = 0; rq < 7; ++rq) {
        int r = rq * 32 + g;                // 0..223; group-uniform guard
        if (r >= BROWS) continue;
        int beg = off[r];
        int end = off[r + 1];
        vfloat4 a00 = {0.f,0.f,0.f,0.f}, a01 = {0.f,0.f,0.f,0.f};
        vfloat4 a10 = {0.f,0.f,0.f,0.f}, a11 = {0.f,0.f,0.f,0.f};
        for (int k0 = beg; k0 < end; k0 += 8) {
            int   cc[8];
            float vv[8];
            #pragma unroll
            for (int u = 0; u < 8; ++u) {
                int2 e = csr[k0 + u];       // LDS broadcast (uniform per group)
                bool ib = (k0 + u) < end;
                cc[u] = ib ? e.x : 0;
                vv[u] = ib ? __int_as_float(e.y) : 0.f;
            }
            half8v s[8];
            #pragma unroll
            for (int u = 0; u < 8; ++u)
                s[u] = supporth[(size_t)cc[u] * H8 + i];
            #pragma unroll
            for (int u = 0; u < 8; ++u) {
                float v = vv[u];
                if (u & 1) {
                    a10.x += v * (float)s[u][0];
                    a10.y += v * (float)s[u][1];
                    a10.z += v * (float)s[u][2];
                    a10.w += v * (float)s[u][3];
                    a11.x += v * (float)s[u][4];
                    a11.y += v * (float)s[u][5];
                    a11.z += v * (float)s[u][6];
                    a11.w += v * (float)s[u][7];
                } else {
                    a00.x += v * (float)s[u][0];
                    a00.y += v * (float)s[u][1];
                    a00.z += v * (float)s[u][2];
                    a00.w += v * (float)s[u][3];
                    a01.x += v * (float)s[u][4];
                    a01.y += v * (float)s[u][5];
                    a01.z += v * (float)s[u][6];
                    a01.w += v * (float)s[u][7];
                }
            }
        }
        int row = base + r;
        if (row < N) {
            vfloat4 r0, r1;
            r0.x = a00.x + a10.x; r0.y = a00.y + a10.y;
            r0.z = a00.z + a10.z; r0.w = a00.w + a10.w;
            r1.x = a01.x + a11.x; r1.y = a01.y + a11.y;
            r1.z = a01.z + a11.z; r1.w = a01.w + a11.w;
            float4* dst = &out4[(size_t)row * F4 + (i << 1)];
            __builtin_nontemporal_store(r0, (vfloat4*)dst);
            __builtin_nontemporal_store(r1, (vfloat4*)(dst + 1));
        }
    }
}

// ============ overflow cleanup (after gather; adds onto its output) ============

__global__ void ovf_scatter_kernel(const float* __restrict__ support,
                                   const int4* __restrict__ ovf,
                                   const int* __restrict__ ovf_count,
                                   float* __restrict__ out, int cap) {
    int gid = blockIdx.x * blockDim.x + threadIdx.x;
    int i = gid >> 5;
    int j = gid & 31;
    int istride = (gridDim.x * blockDim.x) >> 5;
    int cnt = *ovf_count;
    if (cnt > cap) cnt = cap;
    for (; i < cnt; i += istride) {
        int4 q = ovf[i];
        float v = __int_as_float(q.z);
        const float4* s4 = (const float4*)support + (size_t)q.y * F4 + j;
        float4 s = *s4;
        float* o = out + (size_t)q.x * D_FEAT + j * 4;
        unsafeAtomicAdd(o + 0, v * s.x);
        unsafeAtomicAdd(o + 1, v * s.y);
        unsafeAtomicAdd(o + 2, v * s.z);
        unsafeAtomicAdd(o + 3, v * s.w);
    }
}

// ================= fallback 1: R5 fp16 path (device return-atomics) =================

__global__ void convert_kernel(const float4* __restrict__ in,
                               half8v* __restrict__ out, int n8) {
    int t = blockIdx.x * blockDim.x + threadIdx.x;
    if (t >= n8) return;
    float4 a = in[(size_t)t * 2];
    float4 b = in[(size_t)t * 2 + 1];
    half8v h;
    h[0] = (_Float16)a.x; h[1] = (_Float16)a.y;
    h[2] = (_Float16)a.z; h[3] = (_Float16)a.w;
    h[4] = (_Float16)b.x; h[5] = (_Float16)b.y;
    h[6] = (_Float16)b.z; h[7] = (_Float16)b.w;
    out[t] = h;
}

__global__ void gather_half_kernel(const half4v* __restrict__ supporth,
                                   const int* __restrict__ cursor,
                                   const int2* __restrict__ pairs,
                                   float4* __restrict__ out4, int n_nodes) {
    unsigned int t = blockIdx.x * blockDim.x + threadIdx.x;
    unsigned int row = t >> 5;
    unsigned int j = t & 31;
    if (row >= (unsigned int)n_nodes) return;
    int deg = cursor[row];
    if (deg > STRIDE) deg = STRIDE;
    const int2* pr = pairs + (size_t)row * STRIDE;
    int2 z = {0, 0};
    int2 p0 = ((int)j < deg) ? pr[j] : z;
    int2 p1 = ((int)(j + 32) < deg) ? pr[j + 32] : z;
    int   c0 = p0.x;  float v0 = __int_as_float(p0.y);
    int   c1 = p1.x;  float v1 = __int_as_float(p1.y);
    int degr = (deg + 7) & ~7;
    float4 acc[4];
    #pragma unroll
    for (int u = 0; u < 4; ++u) acc[u] = {0.f, 0.f, 0.f, 0.f};
    for (int k = 0; k < degr; k += 8) {
        int   cc[8];
        float vv[8];
        #pragma unroll
        for (int u = 0; u < 8; ++u) {
            int kk = k + u;
            cc[u] = __shfl(kk < 32 ? c0 : c1, kk & 31, 32);
            vv[u] = __shfl(kk < 32 ? v0 : v1, kk & 31, 32);
        }
        half4v s[8];
        #pragma unroll
        for (int u = 0; u < 8; ++u)
            s[u] = supporth[(size_t)cc[u] * H4 + j];
        #pragma unroll
        for (int u = 0; u < 8; ++u) {
            acc[u & 3].x += vv[u] * (float)s[u][0];
            acc[u & 3].y += vv[u] * (float)s[u][1];
            acc[u & 3].z += vv[u] * (float)s[u][2];
            acc[u & 3].w += vv[u] * (float)s[u][3];
        }
    }
    vfloat4 res;
    res.x = (acc[0].x + acc[1].x) + (acc[2].x + acc[3].x);
    res.y = (acc[0].y + acc[1].y) + (acc[2].y + acc[3].y);
    res.z = (acc[0].z + acc[1].z) + (acc[2].z + acc[3].z);
    res.w = (acc[0].w + acc[1].w) + (acc[2].w + acc[3].w);
    __builtin_nontemporal_store(res, (vfloat4*)&out4[(size_t)row * F4 + j]);
}

__global__ void bucket_ilp_kernel(const int* __restrict__ rows,
                                  const int* __restrict__ cols,
                                  const float* __restrict__ vals,
                                  int* __restrict__ cursor,
                                  int* __restrict__ ovf_count,
                                  int2* __restrict__ pairs,
                                  int4* __restrict__ ovf,
                                  int n_edges, int gstride) {
    int tid = blockIdx.x * blockDim.x + threadIdx.x;
    int   r[EPT];
    int   c[EPT];
    float v[EPT];
    int   slot[EPT];
    #pragma unroll
    for (int i = 0; i < EPT; ++i) {
        int e = tid + i * gstride;
        r[i] = (e < n_edges) ? rows[e] : -1;
    }
    #pragma unroll
    for (int i = 0; i < EPT; ++i) {
        int e = tid + i * gstride;
        if (e < n_edges) { c[i] = cols[e]; v[i] = vals[e]; }
    }
    #pragma unroll
    for (int i = 0; i < EPT; ++i)
        slot[i] = (r[i] >= 0) ? atomicAdd(&cursor[r[i]], 1) : 0;
    #pragma unroll
    for (int i = 0; i < EPT; ++i) {
        if (r[i] < 0) continue;
        int2 p;
        p.x = c[i];
        p.y = __float_as_int(v[i]);
        if (slot[i] < STRIDE) {
            pairs[(size_t)r[i] * STRIDE + slot[i]] = p;
        } else {
            int o = atomicAdd(ovf_count, 1);
            if (o < OVF_CAP) {
                int4 q; q.x = r[i]; q.y = p.x; q.z = p.y; q.w = 0;
                ovf[o] = q;
            }
        }
    }
}

// ==================== fallback 2: atomic scatter (R0) ====================

__global__ void gc_scatter_kernel(const float* __restrict__ support,
                                  const float* __restrict__ vals,
                                  const int* __restrict__ rows,
                                  const int* __restrict__ cols,
                                  float* __restrict__ out, int n_edges) {
    unsigned int t = blockIdx.x * blockDim.x + threadIdx.x;
    unsigned int e = t >> 5;
    unsigned int j = t & 31;
    if (e >= (unsigned int)n_edges) return;
    int r = rows[e];
    int c = cols[e];
    float v = vals[e];
    const float4* s4 = reinterpret_cast<const float4*>(support) + (size_t)c * F4 + j;
    float4 s = *s4;
    float* o = out + (size_t)r * D_FEAT + j * 4;
    unsafeAtomicAdd(o + 0, v * s.x);
    unsafeAtomicAdd(o + 1, v * s.y);
    unsafeAtomicAdd(o + 2, v * s.z);
    unsafeAtomicAdd(o + 3, v * s.w);
}

// ============================ launch ============================

extern "C" void kernel_launch(void* const* d_in, const int* in_sizes, int n_in,
                              void* d_out, int out_size, void* d_ws, size_t ws_size,
                              hipStream_t stream) {
    const float* support = (const float*)d_in[0];
    const float* vals    = (const float*)d_in[1];
    const int*   rows    = (const int*)d_in[2];
    const int*   cols    = (const int*)d_in[3];
    float* out = (float*)d_out;

    int E = in_sizes[1];
    int N = in_sizes[0] / D_FEAT;
    int n8 = N * D_FEAT / 8;
    int ND = (N + BROWS - 1) / BROWS;             // 200-row buckets (500)
    int NBLK = (E + BINT * EPT - 1) / (BINT * EPT);  // bin blocks (391)
    int BT = NBLK * BINT;

    char* ws = (char*)d_ws;
    size_t cur = 0;
    auto carve = [&](size_t bytes) -> void* {
        void* p = ws + cur;
        cur += (bytes + 255) & ~(size_t)255;
        return p;
    };

    // ---- primary: dense-list counting-sort binning + fused LDS-CSR bucket gather ----
    {
        size_t save = cur;
        int2*   dense     = (int2*)carve((size_t)512 * CAP * 8);   // 16.8 MB
        int*    gcur      = (int*)carve((size_t)768 * 4);          // [512]+ovf_count
        int4*   ovf       = (int4*)carve((size_t)OVF_CAP * 16);
        half8v* supporth  = (half8v*)carve((size_t)N * D_FEAT * 2);
        if (cur <= ws_size && ND <= 512) {
            int* ovf_count = gcur + 512;
            (void)hipMemsetAsync(gcur, 0, (size_t)513 * 4, stream);
            int cblocks = (n8 + BINT - 1) / BINT;
            phase1_bin_kernel<<<NBLK + cblocks, BINT, 0, stream>>>(
                (const float4*)support, supporth, rows, cols, vals,
                dense, gcur, ovf, ovf_count, E, BT, NBLK, n8);
            bucket_csr_gather_kernel<<<ND, GT, 0, stream>>>(
                supporth, dense, gcur, (float4*)out, N);
            ovf_scatter_kernel<<<128, 256, 0, stream>>>(
                support, ovf, ovf_count, out, OVF_CAP);
            return;
        }
        cur = save;
    }

    // ---- fallback 1: R5 fp16 padded buckets (device return-atomics) ----
    {
        size_t save = cur;
        int*    cursor   = (int*)carve((size_t)(N + 1) * 4);
        int2*   pairs    = (int2*)carve((size_t)N * STRIDE * 8);
        int4*   ovf      = (int4*)carve((size_t)8192 * 16);
        half8v* supporth = (half8v*)carve((size_t)N * D_FEAT * 2);
        if (cur <= ws_size) {
            int* ovf_count = cursor + N;
            int bthreads = (E + EPT - 1) / EPT;
            int bblocks = (bthreads + 255) / 256;
            int gstride = bblocks * 256;
            (void)hipMemsetAsync(cursor, 0, (size_t)(N + 1) * 4, stream);
            convert_kernel<<<(n8 + 255) / 256, 256, 0, stream>>>(
                (const float4*)support, supporth, n8);
            bucket_ilp_kernel<<<bblocks, 256, 0, stream>>>(
                rows, cols, vals, cursor, ovf_count, pairs, ovf, E, gstride);
            unsigned int gthreads = (unsigned int)N * 32;
            gather_half_kernel<<<(gthreads + 255) / 256, 256, 0, stream>>>(
                (const half4v*)supporth, cursor, pairs, (float4*)out, N);
            ovf_scatter_kernel<<<512, 256, 0, stream>>>(
                support, ovf, ovf_count, out, 8192);
            return;
        }
        cur = save;
    }

    // ---- fallback 2: atomic scatter ----
    (void)hipMemsetAsync(d_out, 0, (size_t)out_size * sizeof(float), stream);
    unsigned int total = (unsigned int)E * 32;
    gc_scatter_kernel<<<(total + 255) / 256, 256, 0, stream>>>(
        support, vals, rows, cols, out, E);
}

// Round 10
// 180.395 us; speedup vs baseline: 1.4734x; 1.0255x over previous
//
#include <hip/hip_runtime.h>
#include <hip/hip_bf16.h>
#include <hip/hip_fp16.h>

// GraphConvolution: out = segment_sum(vals[:,None] * support[cols], rows)
// N=100000 nodes, E=1600000 edges, F=128 features, fp32.
//
// Round 17: R16 post-mortem — gather hit prediction (64.8) but is GRID-limited
//  (500 blocks ~ 1.95/CU, occ 35.6%). Dense format makes bucket-splitting
//  free (S1 scans exactly cnt[d]; no per-cell overhead). fixed+phase1 ~110us
//  has been insensitive to 4 phase1 rewrites -> phase1 likely near floor;
//  stop chasing it blind. This round:
//   1. 1000 x 100-row buckets: CAP=2048, GMAXIT=4, ~18KB LDS -> grid 3.9/CU.
//   2. Fuse overflow into gather CSR build (separate oc/oc2 counters; one
//      scalar load when empty) -> ovf_scatter dispatch deleted.
//   3. Bin: 1024-thr blocks (196), runs ~8 at ND=1000 keeps write coalescing;
//      convert blocks fill idle CUs in the merged grid.

#define D_FEAT 128
#define F4 32            // float4s per feature vector
#define H4 32            // half4s per feature vector
#define H8 16            // half8s per feature vector
#define STRIDE 64        // padded slots per row (fallback 1 only)
#define OVF_CAP 131072   // overflow list capacity
#define EPT 8            // edges per thread in binning
#define BINT 1024        // bin threads per block
#define NBINS 1024       // padded bucket count (ND=1000)
#define CAP 2048         // dense per-bucket capacity (lambda=1600, +11 sigma)
#define GMAXIT 4         // gather S1 iterations: 512*4 = 2048 = CAP
#define BROWS 100        // rows per gather bucket
#define GT 512           // gather threads per block
#define CSRCAP (CAP + 64)

typedef float    vfloat4 __attribute__((ext_vector_type(4)));
typedef _Float16 half4v  __attribute__((ext_vector_type(4)));
typedef _Float16 half8v  __attribute__((ext_vector_type(8)));

// ============ phase 1: LDS counting-sort bin -> dense lists + fp32->fp16 convert ============

__global__ __launch_bounds__(BINT) void
phase1_bin_kernel(const float4* __restrict__ support4,
                  half8v* __restrict__ supporth,
                  const int* __restrict__ rows,
                  const int* __restrict__ cols,
                  const float* __restrict__ vals,
                  int2* __restrict__ dense,      // [NBINS][CAP] packed (lrow<<17|col, val)
                  int* __restrict__ gcur,        // [NBINS] cursors; [NBINS]=ovf_count
                  int4* __restrict__ ovf,
                  int* __restrict__ ovf_count,
                  int E, int BT, int NBLK, int n8) {
    int b = blockIdx.x;
    int tid = threadIdx.x;

    if (b >= NBLK) {
        // -------- convert slice --------
        int m = (b - NBLK) * BINT + tid;
        if (m < n8) {
            float4 a0 = support4[(size_t)m * 2];
            float4 a1 = support4[(size_t)m * 2 + 1];
            half8v h;
            h[0] = (_Float16)a0.x; h[1] = (_Float16)a0.y;
            h[2] = (_Float16)a0.z; h[3] = (_Float16)a0.w;
            h[4] = (_Float16)a1.x; h[5] = (_Float16)a1.y;
            h[6] = (_Float16)a1.z; h[7] = (_Float16)a1.w;
            supporth[m] = h;
        }
        return;
    }

    // -------- bin slice: counting sort in LDS, dense reservation writeout --------
    __shared__ int  hist[NBINS];
    __shared__ int  off[NBINS + 1];
    __shared__ int  sstart[NBINS];
    __shared__ int2 sorted[BINT * EPT];   // 64 KB

    for (int i = tid; i < NBINS; i += BINT) hist[i] = 0;
    __syncthreads();

    int t = b * BINT + tid;
    int   r[EPT];
    int   c[EPT];
    float v[EPT];
    int   rk[EPT];

    #pragma unroll
    for (int i = 0; i < EPT; ++i) {
        int e = t + i * BT;
        r[i] = (e < E) ? rows[e] : -1;
    }
    #pragma unroll
    for (int i = 0; i < EPT; ++i) {
        int e = t + i * BT;
        if (e < E) { c[i] = cols[e]; v[i] = vals[e]; }
    }
    // LDS int return-atomics: native ds_add_rtn_u32 (unclamped rank)
    #pragma unroll
    for (int i = 0; i < EPT; ++i)
        rk[i] = (r[i] >= 0) ? atomicAdd(&hist[r[i] / BROWS], 1) : 0;
    __syncthreads();

    // prefix scan of 1024 bins (wave 0; 16 bins/lane serial + wave scan)
    if (tid < 64) {
        int l[16];
        int s = 0;
        #pragma unroll
        for (int k = 0; k < 16; ++k) {
            l[k] = hist[tid * 16 + k];
            s += l[k];
        }
        int inc = s;
        #pragma unroll
        for (int dd = 1; dd < 64; dd <<= 1) {
            int tt = __shfl_up(inc, dd, 64);
            if (tid >= dd) inc += tt;
        }
        int run = inc - s;
        #pragma unroll
        for (int k = 0; k < 16; ++k) {
            off[tid * 16 + k] = run;
            run += l[k];
        }
        if (tid == 63) off[NBINS] = run;
    }
    __syncthreads();

    // scatter into LDS sorted[] (capacity exactly = edges in block)
    #pragma unroll
    for (int i = 0; i < EPT; ++i) {
        if (r[i] < 0) continue;
        int d = r[i] / BROWS;
        int2 q;
        q.x = ((r[i] - d * BROWS) << 17) | c[i];  // c < 2^17, local<100 in 17..24
        q.y = __float_as_int(v[i]);
        sorted[off[d] + rk[i]] = q;
    }
    __syncthreads();

    // one parallel round of per-bucket reservations (<=1024 atomics, distinct threads)
    {
        int l = off[tid + 1] - off[tid];          // tid in [0,1024)
        sstart[tid] = (l > 0) ? atomicAdd(&gcur[tid], l) : 0;
    }
    __syncthreads();

    // copy sorted runs into dense ranges; 16-lane group per bucket
    {
        int grp  = tid >> 4;     // 0..63
        int lane = tid & 15;
        for (int d = grp; d < NBINS; d += 64) {
            int o  = off[d];
            int l  = off[d + 1] - o;
            int st = sstart[d];
            for (int k = lane; k < l; k += 16) {
                int pos = st + k;
                int2 q = sorted[o + k];
                if (pos < CAP) {
                    dense[(size_t)d * CAP + pos] = q;
                } else {
                    int ox = atomicAdd(ovf_count, 1);   // ~never (>=11 sigma)
                    if (ox < OVF_CAP) {
                        int4 e4;
                        e4.x = d * BROWS + ((q.x >> 17) & 255);
                        e4.y = q.x & 0x1FFFF;
                        e4.z = q.y;
                        e4.w = 0;
                        ovf[ox] = e4;
                    }
                }
            }
        }
    }
}

// ====== fused bucket CSR gather: dense-list rank + fused ovf + half8 gather ======
// One block per 100-row bucket d. 512 threads, ~18.5KB LDS -> grid 3.9/CU.
//  S1 : scan cnt[d] dense entries (4 iters), rank via LDS int return-atomic.
//  S1b: (rare) scan ovf list, count own-row entries into oc[].
//  S2 : 32-lane shuffle prefix-scan of cnt+oc -> off.
//  S3 : place dense entries csr[off[r]+rk]; S3b: place ovf at cnt[r]+oc2 rank.
//  S4 : 32 groups x 16 lanes; 4 row-iters (guard r<100); (col,val) by LDS
//       broadcast, 8 independent half8 loads per lane, dual fp32 acc,
//       coalesced nontemporal stores.

__global__ __launch_bounds__(GT) void
bucket_csr_gather_kernel(const half8v* __restrict__ supporth,
                         const int2* __restrict__ dense,
                         const int* __restrict__ gcur,
                         const int4* __restrict__ ovf,
                         const int* __restrict__ ovf_count,
                         float4* __restrict__ out4, int N) {
    __shared__ __align__(16) int cnt[128];
    __shared__ __align__(16) int oc[128];
    __shared__ int oc2[128];
    __shared__ int off[129];
    __shared__ int2 csr[CSRCAP + 8];

    const int d   = blockIdx.x;
    const int tid = threadIdx.x;
    const int2* dbase = dense + (size_t)d * CAP;
    const int base = d * BROWS;

    int total = gcur[d];
    if (total > CAP) total = CAP;
    int ocnt = *ovf_count;
    if (ocnt > OVF_CAP) ocnt = OVF_CAP;

    if (tid < 128) { cnt[tid] = 0; oc[tid] = 0; oc2[tid] = 0; }
    __syncthreads();

    // ---- S1: one-pass load + rank into registers ----
    int2 ent[GMAXIT];
    int  err[GMAXIT];
    int  ernk[GMAXIT];
    #pragma unroll
    for (int it = 0; it < GMAXIT; ++it) {
        int s = tid + it * GT;
        err[it] = -1;
        if (s < total) {
            int2 q = dbase[s];
            int r = (q.x >> 17) & 255;
            ent[it].x = q.x & 0x1FFFF;
            ent[it].y = q.y;
            err[it] = r;
            ernk[it] = atomicAdd(&cnt[r], 1);                // LDS int rtn atomic
        }
    }
    // ---- S1b: count own-row overflow entries (ocnt ~always 0) ----
    if (ocnt > 0) {
        for (int i = tid; i < ocnt; i += GT) {
            int rr = ovf[i].x - base;
            if (rr >= 0 && rr < BROWS) atomicAdd(&oc[rr], 1);
        }
    }
    __syncthreads();

    // ---- S2: prefix scan (cnt+oc)[128] -> off (first 32 lanes) ----
    if (tid < 32) {
        int4 c4 = ((int4*)cnt)[tid];
        int4 o4 = ((int4*)oc)[tid];
        int t0 = c4.x + o4.x;
        int t1 = t0 + c4.y + o4.y;
        int t2 = t1 + c4.z + o4.z;
        int t3 = t2 + c4.w + o4.w;
        int inc = t3;
        #pragma unroll
        for (int dd = 1; dd < 32; dd <<= 1) {
            int t = __shfl_up(inc, dd, 32);
            if (tid >= dd) inc += t;
        }
        int excl = inc - t3;
        off[tid * 4 + 0] = excl;
        off[tid * 4 + 1] = excl + t0;
        off[tid * 4 + 2] = excl + t1;
        off[tid * 4 + 3] = excl + t2;
        if (tid == 31) off[128] = inc;
    }
    __syncthreads();

    // ---- S3: place dense entries ----
    #pragma unroll
    for (int it = 0; it < GMAXIT; ++it) {
        if (err[it] >= 0)
            csr[off[err[it]] + ernk[it]] = ent[it];
    }
    // ---- S3b: place overflow entries after dense ranks ----
    if (ocnt > 0) {
        for (int i = tid; i < ocnt; i += GT) {
            int4 q = ovf[i];
            int rr = q.x - base;
            if (rr >= 0 && rr < BROWS) {
                int idx = off[rr] + cnt[rr] + atomicAdd(&oc2[rr], 1);
                if (idx < CSRCAP) { int2 e; e.x = q.y; e.y = q.z; csr[idx] = e; }
            }
        }
    }
    __syncthreads();

    // ---- S4: gather, 16-lane groups, half8 loads ----
    const int g = tid >> 4;       // group 0..31
    const int i = tid & 15;       // lane in group; feats 8i..8i+7
    for (int rq = 0; rq < 4; ++rq) {
        int r = rq * 32 + g;                // 0..127; group-uniform guard
        if (r >= BROWS) continue;
        int beg = off[r];
        int end = off[r + 1];
        vfloat4 a00 = {0.f,0.f,0.f,0.f}, a01 = {0.f,0.f,0.f,0.f};
        vfloat4 a10 = {0.f,0.f,0.f,0.f}, a11 = {0.f,0.f,0.f,0.f};
        for (int k0 = beg; k0 < end; k0 += 8) {
            int   cc[8];
            float vv[8];
            #pragma unroll
            for (int u = 0; u < 8; ++u) {
                int2 e = csr[k0 + u];       // LDS broadcast (uniform per group)
                bool ib = (k0 + u) < end;
                cc[u] = ib ? e.x : 0;
                vv[u] = ib ? __int_as_float(e.y) : 0.f;
            }
            half8v s[8];
            #pragma unroll
            for (int u = 0; u < 8; ++u)
                s[u] = supporth[(size_t)cc[u] * H8 + i];
            #pragma unroll
            for (int u = 0; u < 8; ++u) {
                float v = vv[u];
                if (u & 1) {
                    a10.x += v * (float)s[u][0];
                    a10.y += v * (float)s[u][1];
                    a10.z += v * (float)s[u][2];
                    a10.w += v * (float)s[u][3];
                    a11.x += v * (float)s[u][4];
                    a11.y += v * (float)s[u][5];
                    a11.z += v * (float)s[u][6];
                    a11.w += v * (float)s[u][7];
                } else {
                    a00.x += v * (float)s[u][0];
                    a00.y += v * (float)s[u][1];
                    a00.z += v * (float)s[u][2];
                    a00.w += v * (float)s[u][3];
                    a01.x += v * (float)s[u][4];
                    a01.y += v * (float)s[u][5];
                    a01.z += v * (float)s[u][6];
                    a01.w += v * (float)s[u][7];
                }
            }
        }
        int row = base + r;
        if (row < N) {
            vfloat4 r0, r1;
            r0.x = a00.x + a10.x; r0.y = a00.y + a10.y;
            r0.z = a00.z + a10.z; r0.w = a00.w + a10.w;
            r1.x = a01.x + a11.x; r1.y = a01.y + a11.y;
            r1.z = a01.z + a11.z; r1.w = a01.w + a11.w;
            float4* dst = &out4[(size_t)row * F4 + (i << 1)];
            __builtin_nontemporal_store(r0, (vfloat4*)dst);
            __builtin_nontemporal_store(r1, (vfloat4*)(dst + 1));
        }
    }
}

// ============ overflow cleanup (fallback 1 only) ============

__global__ void ovf_scatter_kernel(const float* __restrict__ support,
                                   const int4* __restrict__ ovf,
                                   const int* __restrict__ ovf_count,
                                   float* __restrict__ out, int cap) {
    int gid = blockIdx.x * blockDim.x + threadIdx.x;
    int i = gid >> 5;
    int j = gid & 31;
    int istride = (gridDim.x * blockDim.x) >> 5;
    int cnt = *ovf_count;
    if (cnt > cap) cnt = cap;
    for (; i < cnt; i += istride) {
        int4 q = ovf[i];
        float v = __int_as_float(q.z);
        const float4* s4 = (const float4*)support + (size_t)q.y * F4 + j;
        float4 s = *s4;
        float* o = out + (size_t)q.x * D_FEAT + j * 4;
        unsafeAtomicAdd(o + 0, v * s.x);
        unsafeAtomicAdd(o + 1, v * s.y);
        unsafeAtomicAdd(o + 2, v * s.z);
        unsafeAtomicAdd(o + 3, v * s.w);
    }
}

// ================= fallback 1: R5 fp16 path (device return-atomics) =================

__global__ void convert_kernel(const float4* __restrict__ in,
                               half8v* __restrict__ out, int n8) {
    int t = blockIdx.x * blockDim.x + threadIdx.x;
    if (t >= n8) return;
    float4 a = in[(size_t)t * 2];
    float4 b = in[(size_t)t * 2 + 1];
    half8v h;
    h[0] = (_Float16)a.x; h[1] = (_Float16)a.y;
    h[2] = (_Float16)a.z; h[3] = (_Float16)a.w;
    h[4] = (_Float16)b.x; h[5] = (_Float16)b.y;
    h[6] = (_Float16)b.z; h[7] = (_Float16)b.w;
    out[t] = h;
}

__global__ void gather_half_kernel(const half4v* __restrict__ supporth,
                                   const int* __restrict__ cursor,
                                   const int2* __restrict__ pairs,
                                   float4* __restrict__ out4, int n_nodes) {
    unsigned int t = blockIdx.x * blockDim.x + threadIdx.x;
    unsigned int row = t >> 5;
    unsigned int j = t & 31;
    if (row >= (unsigned int)n_nodes) return;
    int deg = cursor[row];
    if (deg > STRIDE) deg = STRIDE;
    const int2* pr = pairs + (size_t)row * STRIDE;
    int2 z = {0, 0};
    int2 p0 = ((int)j < deg) ? pr[j] : z;
    int2 p1 = ((int)(j + 32) < deg) ? pr[j + 32] : z;
    int   c0 = p0.x;  float v0 = __int_as_float(p0.y);
    int   c1 = p1.x;  float v1 = __int_as_float(p1.y);
    int degr = (deg + 7) & ~7;
    float4 acc[4];
    #pragma unroll
    for (int u = 0; u < 4; ++u) acc[u] = {0.f, 0.f, 0.f, 0.f};
    for (int k = 0; k < degr; k += 8) {
        int   cc[8];
        float vv[8];
        #pragma unroll
        for (int u = 0; u < 8; ++u) {
            int kk = k + u;
            cc[u] = __shfl(kk < 32 ? c0 : c1, kk & 31, 32);
            vv[u] = __shfl(kk < 32 ? v0 : v1, kk & 31, 32);
        }
        half4v s[8];
        #pragma unroll
        for (int u = 0; u < 8; ++u)
            s[u] = supporth[(size_t)cc[u] * H4 + j];
        #pragma unroll
        for (int u = 0; u < 8; ++u) {
            acc[u & 3].x += vv[u] * (float)s[u][0];
            acc[u & 3].y += vv[u] * (float)s[u][1];
            acc[u & 3].z += vv[u] * (float)s[u][2];
            acc[u & 3].w += vv[u] * (float)s[u][3];
        }
    }
    vfloat4 res;
    res.x = (acc[0].x + acc[1].x) + (acc[2].x + acc[3].x);
    res.y = (acc[0].y + acc[1].y) + (acc[2].y + acc[3].y);
    res.z = (acc[0].z + acc[1].z) + (acc[2].z + acc[3].z);
    res.w = (acc[0].w + acc[1].w) + (acc[2].w + acc[3].w);
    __builtin_nontemporal_store(res, (vfloat4*)&out4[(size_t)row * F4 + j]);
}

__global__ void bucket_ilp_kernel(const int* __restrict__ rows,
                                  const int* __restrict__ cols,
                                  const float* __restrict__ vals,
                                  int* __restrict__ cursor,
                                  int* __restrict__ ovf_count,
                                  int2* __restrict__ pairs,
                                  int4* __restrict__ ovf,
                                  int n_edges, int gstride) {
    int tid = blockIdx.x * blockDim.x + threadIdx.x;
    int   r[EPT];
    int   c[EPT];
    float v[EPT];
    int   slot[EPT];
    #pragma unroll
    for (int i = 0; i < EPT; ++i) {
        int e = tid + i * gstride;
        r[i] = (e < n_edges) ? rows[e] : -1;
    }
    #pragma unroll
    for (int i = 0; i < EPT; ++i) {
        int e = tid + i * gstride;
        if (e < n_edges) { c[i] = cols[e]; v[i] = vals[e]; }
    }
    #pragma unroll
    for (int i = 0; i < EPT; ++i)
        slot[i] = (r[i] >= 0) ? atomicAdd(&cursor[r[i]], 1) : 0;
    #pragma unroll
    for (int i = 0; i < EPT; ++i) {
        if (r[i] < 0) continue;
        int2 p;
        p.x = c[i];
        p.y = __float_as_int(v[i]);
        if (slot[i] < STRIDE) {
            pairs[(size_t)r[i] * STRIDE + slot[i]] = p;
        } else {
            int o = atomicAdd(ovf_count, 1);
            if (o < OVF_CAP) {
                int4 q; q.x = r[i]; q.y = p.x; q.z = p.y; q.w = 0;
                ovf[o] = q;
            }
        }
    }
}

// ==================== fallback 2: atomic scatter (R0) ====================

__global__ void gc_scatter_kernel(const float* __restrict__ support,
                                  const float* __restrict__ vals,
                                  const int* __restrict__ rows,
                                  const int* __restrict__ cols,
                                  float* __restrict__ out, int n_edges) {
    unsigned int t = blockIdx.x * blockDim.x + threadIdx.x;
    unsigned int e = t >> 5;
    unsigned int j = t & 31;
    if (e >= (unsigned int)n_edges) return;
    int r = rows[e];
    int c = cols[e];
    float v = vals[e];
    const float4* s4 = reinterpret_cast<const float4*>(support) + (size_t)c * F4 + j;
    float4 s = *s4;
    float* o = out + (size_t)r * D_FEAT + j * 4;
    unsafeAtomicAdd(o + 0, v * s.x);
    unsafeAtomicAdd(o + 1, v * s.y);
    unsafeAtomicAdd(o + 2, v * s.z);
    unsafeAtomicAdd(o + 3, v * s.w);
}

// ============================ launch ============================

extern "C" void kernel_launch(void* const* d_in, const int* in_sizes, int n_in,
                              void* d_out, int out_size, void* d_ws, size_t ws_size,
                              hipStream_t stream) {
    const float* support = (const float*)d_in[0];
    const float* vals    = (const float*)d_in[1];
    const int*   rows    = (const int*)d_in[2];
    const int*   cols    = (const int*)d_in[3];
    float* out = (float*)d_out;

    int E = in_sizes[1];
    int N = in_sizes[0] / D_FEAT;
    int n8 = N * D_FEAT / 8;
    int ND = (N + BROWS - 1) / BROWS;             // 100-row buckets (1000)
    int NBLK = (E + BINT * EPT - 1) / (BINT * EPT);  // bin blocks (196)
    int BT = NBLK * BINT;

    char* ws = (char*)d_ws;
    size_t cur = 0;
    auto carve = [&](size_t bytes) -> void* {
        void* p = ws + cur;
        cur += (bytes + 255) & ~(size_t)255;
        return p;
    };

    // ---- primary: dense-list counting-sort binning + fused LDS-CSR bucket gather ----
    {
        size_t save = cur;
        int2*   dense     = (int2*)carve((size_t)NBINS * CAP * 8);   // 16.8 MB
        int*    gcur      = (int*)carve((size_t)(NBINS + 256) * 4);
        int4*   ovf       = (int4*)carve((size_t)OVF_CAP * 16);
        half8v* supporth  = (half8v*)carve((size_t)N * D_FEAT * 2);
        if (cur <= ws_size && ND <= NBINS) {
            int* ovf_count = gcur + NBINS;
            (void)hipMemsetAsync(gcur, 0, (size_t)(NBINS + 1) * 4, stream);
            int cblocks = (n8 + BINT - 1) / BINT;
            phase1_bin_kernel<<<NBLK + cblocks, BINT, 0, stream>>>(
                (const float4*)support, supporth, rows, cols, vals,
                dense, gcur, ovf, ovf_count, E, BT, NBLK, n8);
            bucket_csr_gather_kernel<<<ND, GT, 0, stream>>>(
                supporth, dense, gcur, ovf, ovf_count, (float4*)out, N);
            return;
        }
        cur = save;
    }

    // ---- fallback 1: R5 fp16 padded buckets (device return-atomics) ----
    {
        size_t save = cur;
        int*    cursor   = (int*)carve((size_t)(N + 1) * 4);
        int2*   pairs    = (int2*)carve((size_t)N * STRIDE * 8);
        int4*   ovf      = (int4*)carve((size_t)8192 * 16);
        half8v* supporth = (half8v*)carve((size_t)N * D_FEAT * 2);
        if (cur <= ws_size) {
            int* ovf_count = cursor + N;
            int bthreads = (E + EPT - 1) / EPT;
            int bblocks = (bthreads + 255) / 256;
            int gstride = bblocks * 256;
            (void)hipMemsetAsync(cursor, 0, (size_t)(N + 1) * 4, stream);
            convert_kernel<<<(n8 + 255) / 256, 256, 0, stream>>>(
                (const float4*)support, supporth, n8);
            bucket_ilp_kernel<<<bblocks, 256, 0, stream>>>(
                rows, cols, vals, cursor, ovf_count, pairs, ovf, E, gstride);
            unsigned int gthreads = (unsigned int)N * 32;
            gather_half_kernel<<<(gthreads + 255) / 256, 256, 0, stream>>>(
                (const half4v*)supporth, cursor, pairs, (float4*)out, N);
            ovf_scatter_kernel<<<512, 256, 0, stream>>>(
                support, ovf, ovf_count, out, 8192);
            return;
        }
        cur = save;
    }

    // ---- fallback 2: atomic scatter ----
    (void)hipMemsetAsync(d_out, 0, (size_t)out_size * sizeof(float), stream);
    unsigned int total = (unsigned int)E * 32;
    gc_scatter_kernel<<<(total + 255) / 256, 256, 0, stream>>>(
        support, vals, rows, cols, out, E);
}